// Round 11
// baseline (1935.898 us; speedup 1.0000x reference)
//
#include <hip/hip_runtime.h>

#define S_LEN 2048
#define NHEAD 32
#define HD 80
#define DPAD 96
#define HIDDEN 2560
#define QKV_N 7680

typedef __attribute__((ext_vector_type(8))) short bf16x8;
typedef __attribute__((ext_vector_type(8))) unsigned short u16x8;
typedef __attribute__((ext_vector_type(4))) float f32x4;

__device__ __forceinline__ unsigned short f2bf(float f) {
  unsigned int u = __float_as_uint(f);
  u += 0x7fffu + ((u >> 16) & 1u);   // RNE
  return (unsigned short)(u >> 16);
}
__device__ __forceinline__ float bf2f(unsigned short h) {
  return __uint_as_float(((unsigned int)h) << 16);
}

__device__ __forceinline__ void gload16(const void* g, void* l) {
  __builtin_amdgcn_global_load_lds((const __attribute__((address_space(1))) void*)g,
                                   (__attribute__((address_space(3))) void*)l, 16, 0, 0);
}

// ---------------- fp32 -> bf16 elementwise ----------------
__global__ __launch_bounds__(256) void k_cvt(const float* __restrict__ in,
                                             unsigned short* __restrict__ out, int n4) {
  int i = blockIdx.x * 256 + threadIdx.x;
  if (i >= n4) return;
  float4 v = reinterpret_cast<const float4*>(in)[i];
  ushort4 o;
  o.x = f2bf(v.x); o.y = f2bf(v.y); o.z = f2bf(v.z); o.w = f2bf(v.w);
  reinterpret_cast<ushort4*>(out)[i] = o;
}

// ---------------- fp32 (R x C) -> bf16 transposed (C x R) ----------------
__global__ __launch_bounds__(256) void k_transpose_bf16(const float* __restrict__ in,
                                                        unsigned short* __restrict__ out,
                                                        int R, int C) {
  __shared__ float tile[64][65];
  int tc = blockIdx.x * 64, tr = blockIdx.y * 64;
  for (int i = threadIdx.x; i < 64 * 64; i += 256) {
    int r = i >> 6, c = i & 63;
    tile[r][c] = in[(size_t)(tr + r) * C + (tc + c)];
  }
  __syncthreads();
  for (int i = threadIdx.x; i < 64 * 64; i += 256) {
    int r = i >> 6, c = i & 63;
    out[(size_t)(tc + r) * R + (tr + c)] = f2bf(tile[c][r]);
  }
}

// ---------------- gemm1 (QKV): 256x256, BK=32, 2-deep LDS, 2 blocks/CU ------
// 8 waves, 64 KB LDS -> 2 blocks/CU (16 waves/CU).  Drain vmcnt(0) per tile;
// cross-block TLP covers the drain (m97-era lesson: implicit wave overlap).
// Stage(t+1 -> other buf) right after the entry barrier: buf^1's frags(t-1)
// were read before barrier(t), so DMA-after-barrier(t) is hazard-free; frags
// of t+1 are read after vmcnt(0)+barrier(t+1).  R4-verified swizzle (0 bank
// conflicts); setprio around the 32-MFMA cluster.
__global__ __launch_bounds__(512, 4)
void k_gemm_qkv(const unsigned short* __restrict__ A,
                const unsigned short* __restrict__ Bt,
                const float* __restrict__ bias,
                unsigned short* __restrict__ Cbf,
                int M, int N, int K) {
  __shared__ unsigned short sA[2][8192];
  __shared__ unsigned short sB[2][8192];
  const int nbn = N >> 8;
  const int nwg = (M >> 8) * nbn;
  int wg = blockIdx.x;
  const int cpx = nwg >> 3;          // nwg % 8 == 0
  wg = (wg & 7) * cpx + (wg >> 3);
  const int bm = wg / nbn, bn = wg - bm * nbn;
  const int tid = threadIdx.x;
  const int lane = tid & 63, wave = tid >> 6;
  const int wr = wave >> 2, wc = wave & 3;
  const int lc = lane & 15, lr = lane >> 4;

  const int sub = (lane & 7) ^ (lane >> 3);
  const int rstage = wave * 16 + ((lane >> 3) << 1) + (sub >> 2);
  const int cstage = (sub & 3) * 8;
  const unsigned short* Agp = A + (size_t)(bm * 256 + rstage) * K + cstage;
  const unsigned short* Bgp = Bt + (size_t)(bn * 256 + rstage) * K + cstage;
  const size_t halfoff = (size_t)128 * K;

  const int loff = ((lc >> 1) << 7) + (((((lc & 1) << 2) | lr) ^ (lc >> 1)) << 4);

  f32x4 acc[8][4];
  const f32x4 zero = {0.f, 0.f, 0.f, 0.f};
#pragma unroll
  for (int m = 0; m < 8; ++m)
#pragma unroll
    for (int n = 0; n < 4; ++n) acc[m][n] = zero;

  auto stage = [&](int buf, int t) {
    gload16(Agp + t * 32, &sA[buf][wave * 512]);
    gload16(Agp + halfoff + t * 32, &sA[buf][4096 + wave * 512]);
    gload16(Bgp + t * 32, &sB[buf][wave * 512]);
    gload16(Bgp + halfoff + t * 32, &sB[buf][4096 + wave * 512]);
  };

  const int NT = K >> 5;   // 80
  stage(0, 0);

  for (int t = 0; t < NT; ++t) {
    asm volatile("s_waitcnt vmcnt(0)" ::: "memory");
    __builtin_amdgcn_s_barrier();
    asm volatile("" ::: "memory");
    if (t + 1 < NT) stage((t + 1) & 1, t + 1);

    const char* bufA = (const char*)&sA[t & 1][0];
    const char* bufB = (const char*)&sB[t & 1][0];
    bf16x8 af[8], bfr[4];
#pragma unroll
    for (int mi = 0; mi < 8; ++mi)
      af[mi] = *(const bf16x8*)(bufA + ((wr * 128 + mi * 16) << 6) + loff);
#pragma unroll
    for (int ni = 0; ni < 4; ++ni)
      bfr[ni] = *(const bf16x8*)(bufB + ((wc * 64 + ni * 16) << 6) + loff);

    asm volatile("s_waitcnt lgkmcnt(0)" ::: "memory");
    __builtin_amdgcn_sched_barrier(0);
    __builtin_amdgcn_s_setprio(1);
#pragma unroll
    for (int mi = 0; mi < 8; ++mi)
#pragma unroll
      for (int ni = 0; ni < 4; ++ni)
        acc[mi][ni] = __builtin_amdgcn_mfma_f32_16x16x32_bf16(af[mi], bfr[ni], acc[mi][ni], 0, 0, 0);
    __builtin_amdgcn_s_setprio(0);
  }

  const int rowb = bm * 256 + wr * 128;
  const int colb = bn * 256 + wc * 64;
#pragma unroll
  for (int ni = 0; ni < 4; ++ni) {
    const int col = colb + ni * 16 + lc;
    const float bv = bias[col];
#pragma unroll
    for (int mf = 0; mf < 8; ++mf) {
#pragma unroll
      for (int jj = 0; jj < 4; ++jj) {
        const int row = rowb + mf * 16 + lr * 4 + jj;
        Cbf[(size_t)row * N + col] = f2bf(acc[mf][ni][jj] + bv);
      }
    }
  }
}

// ---------------- gemm2 (out-proj): 128x128, 2-deep LDS, full residency -----
__global__ __launch_bounds__(256, 4)
void k_gemm_out(const unsigned short* __restrict__ A,
                const unsigned short* __restrict__ Bt,
                const float* __restrict__ bias,
                float* __restrict__ Cf,
                int M, int N, int K) {
  __shared__ unsigned short sA[2][4096];
  __shared__ unsigned short sB[2][4096];
  const int nbn = N >> 7;            // 20
  const int nwg = (M >> 7) * nbn;    // 640, % 8 == 0
  int wg = blockIdx.x;
  const int cpx = nwg >> 3;
  wg = (wg & 7) * cpx + (wg >> 3);
  const int bm = wg / nbn, bn = wg - bm * nbn;
  const int tid = threadIdx.x;
  const int lane = tid & 63, wave = tid >> 6;
  const int wr = wave >> 1, wc = wave & 1;
  const int lc = lane & 15, lr = lane >> 4;

  const int sub = (lane & 7) ^ (lane >> 3);
  const int rstage = wave * 16 + ((lane >> 3) << 1) + (sub >> 2);
  const int cstage = (sub & 3) * 8;
  const unsigned short* Agp = A + (size_t)(bm * 128 + rstage) * K + cstage;
  const unsigned short* Bgp = Bt + (size_t)(bn * 128 + rstage) * K + cstage;
  const size_t halfoff = (size_t)64 * K;

  const int loff = ((lc >> 1) << 7) + (((((lc & 1) << 2) | lr) ^ (lc >> 1)) << 4);

  f32x4 acc[4][4];
  const f32x4 zero = {0.f, 0.f, 0.f, 0.f};
#pragma unroll
  for (int m = 0; m < 4; ++m)
#pragma unroll
    for (int n = 0; n < 4; ++n) acc[m][n] = zero;

  auto stage = [&](int buf, int t) {
    gload16(Agp + t * 32, &sA[buf][wave * 512]);
    gload16(Agp + halfoff + t * 32, &sA[buf][2048 + wave * 512]);
    gload16(Bgp + t * 32, &sB[buf][wave * 512]);
    gload16(Bgp + halfoff + t * 32, &sB[buf][2048 + wave * 512]);
  };

  const int NT = K >> 5;   // 80
  stage(0, 0);
  for (int t = 0; t < NT; ++t) {
    asm volatile("s_waitcnt vmcnt(0)" ::: "memory");
    __builtin_amdgcn_s_barrier();
    asm volatile("" ::: "memory");
    if (t + 1 < NT) stage((t + 1) & 1, t + 1);
    const char* bufA = (const char*)&sA[t & 1][0];
    const char* bufB = (const char*)&sB[t & 1][0];
    bf16x8 af[4], bfr[4];
#pragma unroll
    for (int mi = 0; mi < 4; ++mi)
      af[mi] = *(const bf16x8*)(bufA + ((wr * 64 + mi * 16) << 6) + loff);
#pragma unroll
    for (int ni = 0; ni < 4; ++ni)
      bfr[ni] = *(const bf16x8*)(bufB + ((wc * 64 + ni * 16) << 6) + loff);
    asm volatile("s_waitcnt lgkmcnt(0)" ::: "memory");
    __builtin_amdgcn_sched_barrier(0);
    __builtin_amdgcn_s_setprio(1);
#pragma unroll
    for (int mi = 0; mi < 4; ++mi)
#pragma unroll
      for (int ni = 0; ni < 4; ++ni)
        acc[mi][ni] = __builtin_amdgcn_mfma_f32_16x16x32_bf16(af[mi], bfr[ni], acc[mi][ni], 0, 0, 0);
    __builtin_amdgcn_s_setprio(0);
  }

  const int rowb = bm * 128 + wr * 64;
  const int colb = bn * 128 + wc * 64;
#pragma unroll
  for (int ni = 0; ni < 4; ++ni) {
    const int col = colb + ni * 16 + lc;
    const float bv = bias[col];
#pragma unroll
    for (int mf = 0; mf < 4; ++mf) {
#pragma unroll
      for (int jj = 0; jj < 4; ++jj) {
        const int row = rowb + mf * 16 + lr * 4 + jj;
        Cf[(size_t)row * N + col] = acc[mf][ni][jj] + bv;
      }
    }
  }
}

// ---------------- RoPE + head split: qkv -> Q (scaled), K, V^T ----------------
__global__ __launch_bounds__(256) void k_rope(const unsigned short* __restrict__ qkv,
                                              unsigned short* __restrict__ Qw,
                                              unsigned short* __restrict__ Kw,
                                              unsigned short* __restrict__ Vt) {
  const int blk = blockIdx.x;
  const int sc = blk & 31;
  const int bh = blk >> 5;
  const int b = bh >> 5, h = bh & 31;
  const int s0 = sc * 64;
  __shared__ float cs0[64][16], sn0[64][16];
  __shared__ unsigned short vbuf[64][82];
  const int tid = threadIdx.x;
  for (int i = tid; i < 64 * 16; i += 256) {
    int sl = i >> 4, fi = i & 15;
    float ang = (float)(s0 + sl) * __expf(-(float)fi * 0.575646273248511421f);
    cs0[sl][fi] = cosf(ang);
    sn0[sl][fi] = sinf(ang);
  }
  __syncthreads();
  const size_t row0 = (size_t)(b * S_LEN + s0) * QKV_N;
  const size_t obase = ((size_t)bh * S_LEN + s0) * DPAD;
  for (int i = tid; i < 64 * DPAD; i += 256) {
    int sl = i / DPAD, d = i - sl * DPAD;
    float qv = 0.f, kv = 0.f;
    if (d < HD) {
      const unsigned short* rp = qkv + row0 + (size_t)sl * QKV_N + h * HD;
      float q = bf2f(rp[d]), k = bf2f(rp[HIDDEN + d]);
      if (d < 16) {
        float c = cs0[sl][d], s = sn0[sl][d];
        float q2 = bf2f(rp[d + 16]), k2 = bf2f(rp[HIDDEN + d + 16]);
        qv = q * c - q2 * s;
        kv = k * c - k2 * s;
      } else if (d < 32) {
        float c = cs0[sl][d - 16], s = sn0[sl][d - 16];
        float q1 = bf2f(rp[d - 16]), k1 = bf2f(rp[HIDDEN + d - 16]);
        qv = q * c + q1 * s;
        kv = k * c + k1 * s;
      } else {
        qv = q; kv = k;
      }
    }
    Qw[obase + (size_t)sl * DPAD + d] = f2bf(qv * 0.111803398874989485f); // * 80^-0.5
    Kw[obase + (size_t)sl * DPAD + d] = f2bf(kv);
  }
  for (int i = tid; i < 64 * HD; i += 256) {
    int sl = i / HD, d = i - sl * HD;
    vbuf[sl][d] = qkv[row0 + (size_t)sl * QKV_N + 2 * HIDDEN + h * HD + d];
  }
  __syncthreads();
  const size_t vtb = (size_t)bh * DPAD * S_LEN + s0;
  for (int i = tid; i < DPAD * 64; i += 256) {
    int d = i >> 6, sl = i & 63;
    Vt[vtb + (size_t)d * S_LEN + sl] = (d < HD) ? vbuf[sl][d] : (unsigned short)0;
  }
}

// ---------------- flash attention (causal), QBLK=128, KVBLK=64 ----------------
__global__ __launch_bounds__(256, 2) void k_attn(const unsigned short* __restrict__ Qw,
                                                 const unsigned short* __restrict__ Kw,
                                                 const unsigned short* __restrict__ Vt,
                                                 unsigned short* __restrict__ O) {
  __shared__ unsigned short sK[2][64 * 104];
  __shared__ unsigned short sV[2][80 * 72];
  __shared__ unsigned short sP[4][16 * 72];
  const int p = blockIdx.x;
  const int bh = blockIdx.y;
  const int b = bh >> 5, h = bh & 31;
  const int tid = threadIdx.x;
  const int wave = tid >> 6, lane = tid & 63;
  const int lr = lane >> 4, lc = lane & 15;
  unsigned short* Pw = &sP[wave][0];

  const unsigned short* Kh = Kw + (size_t)bh * S_LEN * DPAD;
  const unsigned short* Vh = Vt + (size_t)bh * DPAD * S_LEN;
  const unsigned short* Qh = Qw + (size_t)bh * S_LEN * DPAD;

  const int kr = tid >> 2, kc = (tid & 3) * 24;
  const int vr = tid >> 3, vc = (tid & 7) * 8;

  u16x8 kst0, kst1, kst2, vst0, vst1, vst2;
  auto gload = [&](int t) {
    const unsigned short* Kg = Kh + ((size_t)(t * 64 + kr)) * DPAD + kc;
    kst0 = *(const u16x8*)(Kg);
    kst1 = *(const u16x8*)(Kg + 8);
    kst2 = *(const u16x8*)(Kg + 16);
    const unsigned short* Vg = Vh + (size_t)vr * S_LEN + t * 64 + vc;
    vst0 = *(const u16x8*)(Vg);
    vst1 = *(const u16x8*)(Vg + 32 * S_LEN);
    if (tid < 128) vst2 = *(const u16x8*)(Vg + (size_t)64 * S_LEN);
  };
  auto swrite = [&](int buf) {
    *(u16x8*)&sK[buf][kr * 104 + kc] = kst0;
    *(u16x8*)&sK[buf][kr * 104 + kc + 8] = kst1;
    *(u16x8*)&sK[buf][kr * 104 + kc + 16] = kst2;
    *(u16x8*)&sV[buf][vr * 72 + vc] = vst0;
    *(u16x8*)&sV[buf][(vr + 32) * 72 + vc] = vst1;
    if (tid < 128) *(u16x8*)&sV[buf][(vr + 64) * 72 + vc] = vst2;
  };

  const f32x4 zero = {0.f, 0.f, 0.f, 0.f};

#pragma unroll 1
  for (int qi = 0; qi < 2; ++qi) {
    const int qt = qi ? (15 - p) : p;
    const int nt = 2 * qt + 2;
    const int wbase = qt * 128 + wave * 32;

    bf16x8 qf[2][3];
#pragma unroll
    for (int m = 0; m < 2; ++m)
#pragma unroll
      for (int ks = 0; ks < 3; ++ks)
        qf[m][ks] = *(const bf16x8*)&Qh[(size_t)(wbase + m * 16 + lc) * DPAD + ks * 32 + lr * 8];

    f32x4 oacc[2][5];
#pragma unroll
    for (int m = 0; m < 2; ++m)
#pragma unroll
      for (int n = 0; n < 5; ++n) oacc[m][n] = zero;
    float mrun[2] = {-1e30f, -1e30f}, lrun[2] = {0.f, 0.f};

    gload(0);
    __syncthreads();
    swrite(0);
    int cur = 0;

#pragma unroll 1
    for (int t = 0; t < nt; ++t) {
      __syncthreads();
      if (t + 1 < nt) gload(t + 1);
      const int ktb = t * 64;
      const bool act0 = ktb <= wbase + 15;
      const bool act1 = ktb <= wbase + 31;
      if (act1) {
        const unsigned short* Kc = sK[cur];
        const unsigned short* Vc = sV[cur];
        f32x4 sf[2][4];
#pragma unroll
        for (int n = 0; n < 4; ++n) {
          sf[0][n] = zero; sf[1][n] = zero;
#pragma unroll
          for (int ks = 0; ks < 3; ++ks) {
            bf16x8 kf = *(const bf16x8*)&Kc[(n * 16 + lc) * 104 + ks * 32 + lr * 8];
            if (act0) sf[0][n] = __builtin_amdgcn_mfma_f32_16x16x32_bf16(kf, qf[0][ks], sf[0][n], 0, 0, 0);
            sf[1][n] = __builtin_amdgcn_mfma_f32_16x16x32_bf16(kf, qf[1][ks], sf[1][n], 0, 0, 0);
          }
        }
        bf16x8 vf[5][2];
#pragma unroll
        for (int n = 0; n < 5; ++n)
#pragma unroll
          for (int ks = 0; ks < 2; ++ks)
            vf[n][ks] = *(const bf16x8*)&Vc[(n * 16 + lc) * 72 + ks * 32 + lr * 8];
#pragma unroll
        for (int m = 0; m < 2; ++m) {
          if (m == 0 && !act0) continue;
          const int qrow0 = wbase + m * 16;
          if (ktb + 63 > qrow0) {
#pragma unroll
            for (int n = 0; n < 4; ++n)
#pragma unroll
              for (int j = 0; j < 4; ++j)
                if (ktb + n * 16 + lr * 4 + j > qrow0 + lc) sf[m][n][j] = -1e30f;
          }
          float t0 = sf[m][0][0];
#pragma unroll
          for (int n = 0; n < 4; ++n)
#pragma unroll
            for (int j = 0; j < 4; ++j) t0 = fmaxf(t0, sf[m][n][j]);
          t0 = fmaxf(t0, __shfl_xor(t0, 16));
          t0 = fmaxf(t0, __shfl_xor(t0, 32));
          const float nm = fmaxf(mrun[m], t0);
          const float corrq = __expf(mrun[m] - nm);
          mrun[m] = nm;
          float ps = 0.f;
#pragma unroll
          for (int n = 0; n < 4; ++n)
#pragma unroll
            for (int j = 0; j < 4; ++j) {
              float e = __expf(sf[m][n][j] - nm);
              sf[m][n][j] = e;
              ps += e;
            }
          ps += __shfl_xor(ps, 16);
          ps += __shfl_xor(ps, 32);
          lrun[m] = lrun[m] * corrq + ps;
          float cj[4];
#pragma unroll
          for (int j = 0; j < 4; ++j) cj[j] = __shfl(corrq, lr * 4 + j, 16);
#pragma unroll
          for (int n = 0; n < 5; ++n)
#pragma unroll
            for (int j = 0; j < 4; ++j) oacc[m][n][j] *= cj[j];
#pragma unroll
          for (int n = 0; n < 4; ++n) {
            unsigned lo = (unsigned)f2bf(sf[m][n][0]) | ((unsigned)f2bf(sf[m][n][1]) << 16);
            unsigned hi = (unsigned)f2bf(sf[m][n][2]) | ((unsigned)f2bf(sf[m][n][3]) << 16);
            uint2 u; u.x = lo; u.y = hi;
            *(uint2*)&Pw[lc * 72 + n * 16 + lr * 4] = u;
          }
          asm volatile("" ::: "memory");
          bf16x8 pa0 = *(const bf16x8*)&Pw[lc * 72 + lr * 8];
          bf16x8 pa1 = *(const bf16x8*)&Pw[lc * 72 + 32 + lr * 8];
#pragma unroll
          for (int n = 0; n < 5; ++n) {
            oacc[m][n] = __builtin_amdgcn_mfma_f32_16x16x32_bf16(pa0, vf[n][0], oacc[m][n], 0, 0, 0);
            oacc[m][n] = __builtin_amdgcn_mfma_f32_16x16x32_bf16(pa1, vf[n][1], oacc[m][n], 0, 0, 0);
          }
          asm volatile("" ::: "memory");
        }
      }
      if (t + 1 < nt) swrite(cur ^ 1);
      cur ^= 1;
    }

#pragma unroll
    for (int m = 0; m < 2; ++m) {
      float linv[4];
#pragma unroll
      for (int j = 0; j < 4; ++j) {
        float lj = __shfl(lrun[m], lr * 4 + j, 16);
        linv[j] = 1.f / lj;
      }
      const int q0 = wbase + m * 16 + lr * 4;
#pragma unroll
      for (int n = 0; n < 5; ++n) {
        const int d = n * 16 + lc;
#pragma unroll
        for (int j = 0; j < 4; ++j)
          O[((size_t)(b * S_LEN) + q0 + j) * HIDDEN + h * HD + d] = f2bf(oacc[m][n][j] * linv[j]);
      }
    }
  }
}

extern "C" void kernel_launch(void* const* d_in, const int* in_sizes, int n_in,
                              void* d_out, int out_size, void* d_ws, size_t ws_size,
                              hipStream_t stream) {
  (void)in_sizes; (void)n_in; (void)out_size; (void)ws_size;
  const float* hidden  = (const float*)d_in[1];
  const float* w_qkv   = (const float*)d_in[2];
  const float* b_qkv   = (const float*)d_in[3];
  const float* w_dense = (const float*)d_in[4];
  const float* b_dense = (const float*)d_in[5];
  char* ws = (char*)d_ws;
  unsigned short* Abf   = (unsigned short*)(ws + 0);          // 4096x2560 bf16
  unsigned short* Wqkvt = (unsigned short*)(ws + 20971520);   // 7680x2560 bf16
  unsigned short* Wdt   = (unsigned short*)(ws + 60293120);   // 2560x2560 bf16
  unsigned short* QKVb  = (unsigned short*)(ws + 73400320);   // 4096x7680 bf16
  unsigned short* Qw    = (unsigned short*)(ws + 136314880);  // 64x2048x96 bf16
  unsigned short* Kw    = (unsigned short*)(ws + 161480704);
  unsigned short* Vt    = (unsigned short*)(ws + 186646528);
  unsigned short* Obf   = (unsigned short*)(ws + 211812352);  // 4096x2560 bf16

  k_cvt<<<10240, 256, 0, stream>>>(hidden, Abf, 2621440);
  k_transpose_bf16<<<dim3(120, 40), 256, 0, stream>>>(w_qkv, Wqkvt, 2560, 7680);
  k_transpose_bf16<<<dim3(40, 40), 256, 0, stream>>>(w_dense, Wdt, 2560, 2560);
  k_gemm_qkv<<<480, 512, 0, stream>>>(Abf, Wqkvt, b_qkv, QKVb, 4096, 7680, 2560);
  k_rope<<<2048, 256, 0, stream>>>(QKVb, Qw, Kw, Vt);
  k_attn<<<dim3(8, 64), 256, 0, stream>>>(Qw, Kw, Vt, Obf);
  k_gemm_out<<<640, 256, 0, stream>>>(Obf, Wdt, b_dense, (float*)d_out, 4096, 2560, 2560);
}

// Round 12
// 434.189 us; speedup vs baseline: 4.4587x; 4.4587x over previous
//
#include <hip/hip_runtime.h>

#define S_LEN 2048
#define NHEAD 32
#define HD 80
#define DPAD 96
#define HIDDEN 2560
#define QKV_N 7680

typedef __attribute__((ext_vector_type(8))) short bf16x8;
typedef __attribute__((ext_vector_type(8))) unsigned short u16x8;
typedef __attribute__((ext_vector_type(4))) float f32x4;

__device__ __forceinline__ unsigned short f2bf(float f) {
  unsigned int u = __float_as_uint(f);
  u += 0x7fffu + ((u >> 16) & 1u);   // RNE
  return (unsigned short)(u >> 16);
}
__device__ __forceinline__ float bf2f(unsigned short h) {
  return __uint_as_float(((unsigned int)h) << 16);
}

__device__ __forceinline__ void gload16(const void* g, void* l) {
  __builtin_amdgcn_global_load_lds((const __attribute__((address_space(1))) void*)g,
                                   (__attribute__((address_space(3))) void*)l, 16, 0, 0);
}

// ---------------- fp32 -> bf16 elementwise ----------------
__global__ __launch_bounds__(256) void k_cvt(const float* __restrict__ in,
                                             unsigned short* __restrict__ out, int n4) {
  int i = blockIdx.x * 256 + threadIdx.x;
  if (i >= n4) return;
  float4 v = reinterpret_cast<const float4*>(in)[i];
  ushort4 o;
  o.x = f2bf(v.x); o.y = f2bf(v.y); o.z = f2bf(v.z); o.w = f2bf(v.w);
  reinterpret_cast<ushort4*>(out)[i] = o;
}

// ---------------- fp32 (R x C) -> bf16 transposed (C x R), vectorized -------
// loads float4 (coalesced), stores u16x8 along the contiguous output dim.
__global__ __launch_bounds__(256) void k_transpose_bf16(const float* __restrict__ in,
                                                        unsigned short* __restrict__ out,
                                                        int R, int C) {
  __shared__ float tile[64][68];   // stride 68 floats = 272B rows (16B aligned)
  int tc = blockIdx.x * 64, tr = blockIdx.y * 64;
  for (int i = threadIdx.x; i < 64 * 16; i += 256) {
    int r = i >> 4, c4 = i & 15;
    float4 v = *(const float4*)&in[(size_t)(tr + r) * C + tc + c4 * 4];
    *(float4*)&tile[r][c4 * 4] = v;
  }
  __syncthreads();
  // out[(tc+c)*R + tr + ro*8 + j] = tile[ro*8+j][c]; wave-uniform ro, c = lane
  for (int i = threadIdx.x; i < 8 * 64; i += 256) {
    int ro = i >> 6, c = i & 63;
    u16x8 v;
#pragma unroll
    for (int j = 0; j < 8; ++j) v[j] = f2bf(tile[ro * 8 + j][c]);
    *(u16x8*)&out[(size_t)(tc + c) * R + tr + ro * 8] = v;
  }
}

// ---------------- gemm1 (QKV): 256x256, BK=32, R10-exact structure ----------
// 8 waves, 4-deep circular LDS, single entry barrier + counted vmcnt(8),
// verified swizzle (0 bank conflicts), setprio around 32-MFMA cluster.
// NOTE: 128-VGPR accumulator => max 2 waves/EU (R11 spill lesson).
__global__ __launch_bounds__(512, 2)
void k_gemm_qkv(const unsigned short* __restrict__ A,
                const unsigned short* __restrict__ Bt,
                const float* __restrict__ bias,
                unsigned short* __restrict__ Cbf,
                int M, int N, int K) {
  __shared__ unsigned short sA[4][8192];
  __shared__ unsigned short sB[4][8192];
  const int nbn = N >> 8;
  const int nwg = (M >> 8) * nbn;
  int wg = blockIdx.x;
  const int cpx = nwg >> 3;          // nwg % 8 == 0
  wg = (wg & 7) * cpx + (wg >> 3);
  const int bm = wg / nbn, bn = wg - bm * nbn;
  const int tid = threadIdx.x;
  const int lane = tid & 63, wave = tid >> 6;
  const int wr = wave >> 2, wc = wave & 3;
  const int lc = lane & 15, lr = lane >> 4;

  const int sub = (lane & 7) ^ (lane >> 3);
  const int rstage = wave * 16 + ((lane >> 3) << 1) + (sub >> 2);
  const int cstage = (sub & 3) * 8;
  const unsigned short* Agp = A + (size_t)(bm * 256 + rstage) * K + cstage;
  const unsigned short* Bgp = Bt + (size_t)(bn * 256 + rstage) * K + cstage;
  const size_t halfoff = (size_t)128 * K;

  const int loff = ((lc >> 1) << 7) + (((((lc & 1) << 2) | lr) ^ (lc >> 1)) << 4);

  f32x4 acc[8][4];
  const f32x4 zero = {0.f, 0.f, 0.f, 0.f};
#pragma unroll
  for (int m = 0; m < 8; ++m)
#pragma unroll
    for (int n = 0; n < 4; ++n) acc[m][n] = zero;

  auto stage = [&](int buf, int t) {
    gload16(Agp + t * 32, &sA[buf][wave * 512]);
    gload16(Agp + halfoff + t * 32, &sA[buf][4096 + wave * 512]);
    gload16(Bgp + t * 32, &sB[buf][wave * 512]);
    gload16(Bgp + halfoff + t * 32, &sB[buf][4096 + wave * 512]);
  };

  const int NT = K >> 5;   // 80
#pragma unroll
  for (int t = 0; t < 3; ++t) stage(t, t);

  const int nj = NT >> 2;
  for (int j = 0; j < nj; ++j) {
#pragma unroll
    for (int to = 0; to < 4; ++to) {
      const int t = (j << 2) + to;
      if (t < NT - 2)       asm volatile("s_waitcnt vmcnt(8)" ::: "memory");
      else if (t == NT - 2) asm volatile("s_waitcnt vmcnt(4)" ::: "memory");
      else                  asm volatile("s_waitcnt vmcnt(0)" ::: "memory");
      __builtin_amdgcn_s_barrier();
      asm volatile("" ::: "memory");

      const char* bufA = (const char*)&sA[to][0];
      const char* bufB = (const char*)&sB[to][0];
      bf16x8 af[8], bfr[4];
#pragma unroll
      for (int mi = 0; mi < 8; ++mi)
        af[mi] = *(const bf16x8*)(bufA + ((wr * 128 + mi * 16) << 6) + loff);
#pragma unroll
      for (int ni = 0; ni < 4; ++ni)
        bfr[ni] = *(const bf16x8*)(bufB + ((wc * 64 + ni * 16) << 6) + loff);

      if (t + 3 < NT) stage((to + 3) & 3, t + 3);

      asm volatile("s_waitcnt lgkmcnt(0)" ::: "memory");
      __builtin_amdgcn_sched_barrier(0);
      __builtin_amdgcn_s_setprio(1);
#pragma unroll
      for (int mi = 0; mi < 8; ++mi)
#pragma unroll
        for (int ni = 0; ni < 4; ++ni)
          acc[mi][ni] = __builtin_amdgcn_mfma_f32_16x16x32_bf16(af[mi], bfr[ni], acc[mi][ni], 0, 0, 0);
      __builtin_amdgcn_s_setprio(0);
    }
  }

  const int rowb = bm * 256 + wr * 128;
  const int colb = bn * 256 + wc * 64;
#pragma unroll
  for (int ni = 0; ni < 4; ++ni) {
    const int col = colb + ni * 16 + lc;
    const float bv = bias[col];
#pragma unroll
    for (int mf = 0; mf < 8; ++mf) {
#pragma unroll
      for (int jj = 0; jj < 4; ++jj) {
        const int row = rowb + mf * 16 + lr * 4 + jj;
        Cbf[(size_t)row * N + col] = f2bf(acc[mf][ni][jj] + bv);
      }
    }
  }
}

// ---------------- gemm2 (out-proj): 128x128, 2-deep LDS, full residency -----
__global__ __launch_bounds__(256, 4)
void k_gemm_out(const unsigned short* __restrict__ A,
                const unsigned short* __restrict__ Bt,
                const float* __restrict__ bias,
                float* __restrict__ Cf,
                int M, int N, int K) {
  __shared__ unsigned short sA[2][4096];
  __shared__ unsigned short sB[2][4096];
  const int nbn = N >> 7;            // 20
  const int nwg = (M >> 7) * nbn;    // 640, % 8 == 0
  int wg = blockIdx.x;
  const int cpx = nwg >> 3;
  wg = (wg & 7) * cpx + (wg >> 3);
  const int bm = wg / nbn, bn = wg - bm * nbn;
  const int tid = threadIdx.x;
  const int lane = tid & 63, wave = tid >> 6;
  const int wr = wave >> 1, wc = wave & 1;
  const int lc = lane & 15, lr = lane >> 4;

  const int sub = (lane & 7) ^ (lane >> 3);
  const int rstage = wave * 16 + ((lane >> 3) << 1) + (sub >> 2);
  const int cstage = (sub & 3) * 8;
  const unsigned short* Agp = A + (size_t)(bm * 128 + rstage) * K + cstage;
  const unsigned short* Bgp = Bt + (size_t)(bn * 128 + rstage) * K + cstage;
  const size_t halfoff = (size_t)64 * K;

  const int loff = ((lc >> 1) << 7) + (((((lc & 1) << 2) | lr) ^ (lc >> 1)) << 4);

  f32x4 acc[4][4];
  const f32x4 zero = {0.f, 0.f, 0.f, 0.f};
#pragma unroll
  for (int m = 0; m < 4; ++m)
#pragma unroll
    for (int n = 0; n < 4; ++n) acc[m][n] = zero;

  auto stage = [&](int buf, int t) {
    gload16(Agp + t * 32, &sA[buf][wave * 512]);
    gload16(Agp + halfoff + t * 32, &sA[buf][2048 + wave * 512]);
    gload16(Bgp + t * 32, &sB[buf][wave * 512]);
    gload16(Bgp + halfoff + t * 32, &sB[buf][2048 + wave * 512]);
  };

  const int NT = K >> 5;   // 80
  stage(0, 0);
  for (int t = 0; t < NT; ++t) {
    asm volatile("s_waitcnt vmcnt(0)" ::: "memory");
    __builtin_amdgcn_s_barrier();
    asm volatile("" ::: "memory");
    if (t + 1 < NT) stage((t + 1) & 1, t + 1);
    const char* bufA = (const char*)&sA[t & 1][0];
    const char* bufB = (const char*)&sB[t & 1][0];
    bf16x8 af[4], bfr[4];
#pragma unroll
    for (int mi = 0; mi < 4; ++mi)
      af[mi] = *(const bf16x8*)(bufA + ((wr * 64 + mi * 16) << 6) + loff);
#pragma unroll
    for (int ni = 0; ni < 4; ++ni)
      bfr[ni] = *(const bf16x8*)(bufB + ((wc * 64 + ni * 16) << 6) + loff);
    asm volatile("s_waitcnt lgkmcnt(0)" ::: "memory");
    __builtin_amdgcn_sched_barrier(0);
    __builtin_amdgcn_s_setprio(1);
#pragma unroll
    for (int mi = 0; mi < 4; ++mi)
#pragma unroll
      for (int ni = 0; ni < 4; ++ni)
        acc[mi][ni] = __builtin_amdgcn_mfma_f32_16x16x32_bf16(af[mi], bfr[ni], acc[mi][ni], 0, 0, 0);
    __builtin_amdgcn_s_setprio(0);
  }

  const int rowb = bm * 128 + wr * 64;
  const int colb = bn * 128 + wc * 64;
#pragma unroll
  for (int ni = 0; ni < 4; ++ni) {
    const int col = colb + ni * 16 + lc;
    const float bv = bias[col];
#pragma unroll
    for (int mf = 0; mf < 4; ++mf) {
#pragma unroll
      for (int jj = 0; jj < 4; ++jj) {
        const int row = rowb + mf * 16 + lr * 4 + jj;
        Cf[(size_t)row * N + col] = acc[mf][ni][jj] + bv;
      }
    }
  }
}

// ---------------- RoPE + head split (vectorized): qkv -> Q, K, V^T ----------
// All global loads/stores are u16x8 (16B).  Octet index o is wave-uniform
// (o = i>>6) so rotation branches don't diverge within a wave.
__global__ __launch_bounds__(256) void k_rope(const unsigned short* __restrict__ qkv,
                                              unsigned short* __restrict__ Qw,
                                              unsigned short* __restrict__ Kw,
                                              unsigned short* __restrict__ Vt) {
  const int blk = blockIdx.x;
  const int sc = blk & 31;
  const int bh = blk >> 5;
  const int b = bh >> 5, h = bh & 31;
  const int s0 = sc * 64;
  __shared__ float cs0[64][16], sn0[64][16];
  __shared__ unsigned short vbuf[64][88];   // 176B rows: 16B-aligned
  const int tid = threadIdx.x;
  for (int i = tid; i < 64 * 16; i += 256) {
    int sl = i >> 4, fi = i & 15;
    float ang = (float)(s0 + sl) * __expf(-(float)fi * 0.575646273248511421f);
    cs0[sl][fi] = cosf(ang);
    sn0[sl][fi] = sinf(ang);
  }
  const size_t row0 = (size_t)(b * S_LEN + s0) * QKV_N;
  // V: 64 rows x 10 octets, vectorized load -> LDS
  for (int i = tid; i < 10 * 64; i += 256) {
    int o = i >> 6, sl = i & 63;
    *(u16x8*)&vbuf[sl][o * 8] =
        *(const u16x8*)&qkv[row0 + (size_t)sl * QKV_N + 2 * HIDDEN + h * HD + o * 8];
  }
  __syncthreads();
  // Q/K rope: 64 rows x 12 octets (o>=10 -> zero pad)
  const size_t obase = ((size_t)bh * S_LEN + s0) * DPAD;
  const float SCALE = 0.111803398874989485f;  // 80^-0.5
  for (int i = tid; i < 12 * 64; i += 256) {
    int o = i >> 6, sl = i & 63;
    u16x8 outq = {0, 0, 0, 0, 0, 0, 0, 0};
    u16x8 outk = {0, 0, 0, 0, 0, 0, 0, 0};
    if (o < 10) {
      const unsigned short* rp = qkv + row0 + (size_t)sl * QKV_N + h * HD;
      u16x8 xq = *(const u16x8*)(rp + o * 8);
      u16x8 xk = *(const u16x8*)(rp + HIDDEN + o * 8);
      if (o < 2) {
        u16x8 yq = *(const u16x8*)(rp + (o + 2) * 8);
        u16x8 yk = *(const u16x8*)(rp + HIDDEN + (o + 2) * 8);
#pragma unroll
        for (int j = 0; j < 8; ++j) {
          float c = cs0[sl][o * 8 + j], s = sn0[sl][o * 8 + j];
          outq[j] = f2bf((bf2f(xq[j]) * c - bf2f(yq[j]) * s) * SCALE);
          outk[j] = f2bf(bf2f(xk[j]) * c - bf2f(yk[j]) * s);
        }
      } else if (o < 4) {
        u16x8 yq = *(const u16x8*)(rp + (o - 2) * 8);
        u16x8 yk = *(const u16x8*)(rp + HIDDEN + (o - 2) * 8);
#pragma unroll
        for (int j = 0; j < 8; ++j) {
          float c = cs0[sl][(o - 2) * 8 + j], s = sn0[sl][(o - 2) * 8 + j];
          outq[j] = f2bf((bf2f(xq[j]) * c + bf2f(yq[j]) * s) * SCALE);
          outk[j] = f2bf(bf2f(xk[j]) * c + bf2f(yk[j]) * s);
        }
      } else {
#pragma unroll
        for (int j = 0; j < 8; ++j) {
          outq[j] = f2bf(bf2f(xq[j]) * SCALE);
          outk[j] = xk[j];
        }
      }
    }
    *(u16x8*)&Qw[obase + (size_t)sl * DPAD + o * 8] = outq;
    *(u16x8*)&Kw[obase + (size_t)sl * DPAD + o * 8] = outk;
  }
  // V^T: only rows d<80 are ever read by attn
  const size_t vtb = (size_t)bh * DPAD * S_LEN + s0;
  for (int i = tid; i < 80 * 8; i += 256) {
    int d = i >> 3, so = i & 7;
    u16x8 v;
#pragma unroll
    for (int j = 0; j < 8; ++j) v[j] = vbuf[so * 8 + j][d];
    *(u16x8*)&Vt[vtb + (size_t)d * S_LEN + so * 8] = v;
  }
}

// ---------------- flash attention (causal), QBLK=128, KVBLK=64 ----------------
__global__ __launch_bounds__(256, 2) void k_attn(const unsigned short* __restrict__ Qw,
                                                 const unsigned short* __restrict__ Kw,
                                                 const unsigned short* __restrict__ Vt,
                                                 unsigned short* __restrict__ O) {
  __shared__ unsigned short sK[2][64 * 104];
  __shared__ unsigned short sV[2][80 * 72];
  __shared__ unsigned short sP[4][16 * 72];
  const int p = blockIdx.x;
  const int bh = blockIdx.y;
  const int b = bh >> 5, h = bh & 31;
  const int tid = threadIdx.x;
  const int wave = tid >> 6, lane = tid & 63;
  const int lr = lane >> 4, lc = lane & 15;
  unsigned short* Pw = &sP[wave][0];

  const unsigned short* Kh = Kw + (size_t)bh * S_LEN * DPAD;
  const unsigned short* Vh = Vt + (size_t)bh * DPAD * S_LEN;
  const unsigned short* Qh = Qw + (size_t)bh * S_LEN * DPAD;

  const int kr = tid >> 2, kc = (tid & 3) * 24;
  const int vr = tid >> 3, vc = (tid & 7) * 8;

  u16x8 kst0, kst1, kst2, vst0, vst1, vst2;
  auto gload = [&](int t) {
    const unsigned short* Kg = Kh + ((size_t)(t * 64 + kr)) * DPAD + kc;
    kst0 = *(const u16x8*)(Kg);
    kst1 = *(const u16x8*)(Kg + 8);
    kst2 = *(const u16x8*)(Kg + 16);
    const unsigned short* Vg = Vh + (size_t)vr * S_LEN + t * 64 + vc;
    vst0 = *(const u16x8*)(Vg);
    vst1 = *(const u16x8*)(Vg + 32 * S_LEN);
    if (tid < 128) vst2 = *(const u16x8*)(Vg + (size_t)64 * S_LEN);
  };
  auto swrite = [&](int buf) {
    *(u16x8*)&sK[buf][kr * 104 + kc] = kst0;
    *(u16x8*)&sK[buf][kr * 104 + kc + 8] = kst1;
    *(u16x8*)&sK[buf][kr * 104 + kc + 16] = kst2;
    *(u16x8*)&sV[buf][vr * 72 + vc] = vst0;
    *(u16x8*)&sV[buf][(vr + 32) * 72 + vc] = vst1;
    if (tid < 128) *(u16x8*)&sV[buf][(vr + 64) * 72 + vc] = vst2;
  };

  const f32x4 zero = {0.f, 0.f, 0.f, 0.f};

#pragma unroll 1
  for (int qi = 0; qi < 2; ++qi) {
    const int qt = qi ? (15 - p) : p;
    const int nt = 2 * qt + 2;
    const int wbase = qt * 128 + wave * 32;

    bf16x8 qf[2][3];
#pragma unroll
    for (int m = 0; m < 2; ++m)
#pragma unroll
      for (int ks = 0; ks < 3; ++ks)
        qf[m][ks] = *(const bf16x8*)&Qh[(size_t)(wbase + m * 16 + lc) * DPAD + ks * 32 + lr * 8];

    f32x4 oacc[2][5];
#pragma unroll
    for (int m = 0; m < 2; ++m)
#pragma unroll
      for (int n = 0; n < 5; ++n) oacc[m][n] = zero;
    float mrun[2] = {-1e30f, -1e30f}, lrun[2] = {0.f, 0.f};

    gload(0);
    __syncthreads();
    swrite(0);
    int cur = 0;

#pragma unroll 1
    for (int t = 0; t < nt; ++t) {
      __syncthreads();
      if (t + 1 < nt) gload(t + 1);
      const int ktb = t * 64;
      const bool act0 = ktb <= wbase + 15;
      const bool act1 = ktb <= wbase + 31;
      if (act1) {
        const unsigned short* Kc = sK[cur];
        const unsigned short* Vc = sV[cur];
        f32x4 sf[2][4];
#pragma unroll
        for (int n = 0; n < 4; ++n) {
          sf[0][n] = zero; sf[1][n] = zero;
#pragma unroll
          for (int ks = 0; ks < 3; ++ks) {
            bf16x8 kf = *(const bf16x8*)&Kc[(n * 16 + lc) * 104 + ks * 32 + lr * 8];
            if (act0) sf[0][n] = __builtin_amdgcn_mfma_f32_16x16x32_bf16(kf, qf[0][ks], sf[0][n], 0, 0, 0);
            sf[1][n] = __builtin_amdgcn_mfma_f32_16x16x32_bf16(kf, qf[1][ks], sf[1][n], 0, 0, 0);
          }
        }
        bf16x8 vf[5][2];
#pragma unroll
        for (int n = 0; n < 5; ++n)
#pragma unroll
          for (int ks = 0; ks < 2; ++ks)
            vf[n][ks] = *(const bf16x8*)&Vc[(n * 16 + lc) * 72 + ks * 32 + lr * 8];
#pragma unroll
        for (int m = 0; m < 2; ++m) {
          if (m == 0 && !act0) continue;
          const int qrow0 = wbase + m * 16;
          if (ktb + 63 > qrow0) {
#pragma unroll
            for (int n = 0; n < 4; ++n)
#pragma unroll
              for (int j = 0; j < 4; ++j)
                if (ktb + n * 16 + lr * 4 + j > qrow0 + lc) sf[m][n][j] = -1e30f;
          }
          float t0 = sf[m][0][0];
#pragma unroll
          for (int n = 0; n < 4; ++n)
#pragma unroll
            for (int j = 0; j < 4; ++j) t0 = fmaxf(t0, sf[m][n][j]);
          t0 = fmaxf(t0, __shfl_xor(t0, 16));
          t0 = fmaxf(t0, __shfl_xor(t0, 32));
          const float nm = fmaxf(mrun[m], t0);
          const float corrq = __expf(mrun[m] - nm);
          mrun[m] = nm;
          float ps = 0.f;
#pragma unroll
          for (int n = 0; n < 4; ++n)
#pragma unroll
            for (int j = 0; j < 4; ++j) {
              float e = __expf(sf[m][n][j] - nm);
              sf[m][n][j] = e;
              ps += e;
            }
          ps += __shfl_xor(ps, 16);
          ps += __shfl_xor(ps, 32);
          lrun[m] = lrun[m] * corrq + ps;
          float cj[4];
#pragma unroll
          for (int j = 0; j < 4; ++j) cj[j] = __shfl(corrq, lr * 4 + j, 16);
#pragma unroll
          for (int n = 0; n < 5; ++n)
#pragma unroll
            for (int j = 0; j < 4; ++j) oacc[m][n][j] *= cj[j];
#pragma unroll
          for (int n = 0; n < 4; ++n) {
            unsigned lo = (unsigned)f2bf(sf[m][n][0]) | ((unsigned)f2bf(sf[m][n][1]) << 16);
            unsigned hi = (unsigned)f2bf(sf[m][n][2]) | ((unsigned)f2bf(sf[m][n][3]) << 16);
            uint2 u; u.x = lo; u.y = hi;
            *(uint2*)&Pw[lc * 72 + n * 16 + lr * 4] = u;
          }
          asm volatile("" ::: "memory");
          bf16x8 pa0 = *(const bf16x8*)&Pw[lc * 72 + lr * 8];
          bf16x8 pa1 = *(const bf16x8*)&Pw[lc * 72 + 32 + lr * 8];
#pragma unroll
          for (int n = 0; n < 5; ++n) {
            oacc[m][n] = __builtin_amdgcn_mfma_f32_16x16x32_bf16(pa0, vf[n][0], oacc[m][n], 0, 0, 0);
            oacc[m][n] = __builtin_amdgcn_mfma_f32_16x16x32_bf16(pa1, vf[n][1], oacc[m][n], 0, 0, 0);
          }
          asm volatile("" ::: "memory");
        }
      }
      if (t + 1 < nt) swrite(cur ^ 1);
      cur ^= 1;
    }

#pragma unroll
    for (int m = 0; m < 2; ++m) {
      float linv[4];
#pragma unroll
      for (int j = 0; j < 4; ++j) {
        float lj = __shfl(lrun[m], lr * 4 + j, 16);
        linv[j] = 1.f / lj;
      }
      const int q0 = wbase + m * 16 + lr * 4;
#pragma unroll
      for (int n = 0; n < 5; ++n) {
        const int d = n * 16 + lc;
#pragma unroll
        for (int j = 0; j < 4; ++j)
          O[((size_t)(b * S_LEN) + q0 + j) * HIDDEN + h * HD + d] = f2bf(oacc[m][n][j] * linv[j]);
      }
    }
  }
}

extern "C" void kernel_launch(void* const* d_in, const int* in_sizes, int n_in,
                              void* d_out, int out_size, void* d_ws, size_t ws_size,
                              hipStream_t stream) {
  (void)in_sizes; (void)n_in; (void)out_size; (void)ws_size;
  const float* hidden  = (const float*)d_in[1];
  const float* w_qkv   = (const float*)d_in[2];
  const float* b_qkv   = (const float*)d_in[3];
  const float* w_dense = (const float*)d_in[4];
  const float* b_dense = (const float*)d_in[5];
  char* ws = (char*)d_ws;
  unsigned short* Abf   = (unsigned short*)(ws + 0);          // 4096x2560 bf16
  unsigned short* Wqkvt = (unsigned short*)(ws + 20971520);   // 7680x2560 bf16
  unsigned short* Wdt   = (unsigned short*)(ws + 60293120);   // 2560x2560 bf16
  unsigned short* QKVb  = (unsigned short*)(ws + 73400320);   // 4096x7680 bf16
  unsigned short* Qw    = (unsigned short*)(ws + 136314880);  // 64x2048x96 bf16
  unsigned short* Kw    = (unsigned short*)(ws + 161480704);
  unsigned short* Vt    = (unsigned short*)(ws + 186646528);
  unsigned short* Obf   = (unsigned short*)(ws + 211812352);  // 4096x2560 bf16

  k_cvt<<<10240, 256, 0, stream>>>(hidden, Abf, 2621440);
  k_transpose_bf16<<<dim3(120, 40), 256, 0, stream>>>(w_qkv, Wqkvt, 2560, 7680);
  k_transpose_bf16<<<dim3(40, 40), 256, 0, stream>>>(w_dense, Wdt, 2560, 2560);
  k_gemm_qkv<<<480, 512, 0, stream>>>(Abf, Wqkvt, b_qkv, QKVb, 4096, 7680, 2560);
  k_rope<<<2048, 256, 0, stream>>>(QKVb, Qw, Kw, Vt);
  k_attn<<<dim3(8, 64), 256, 0, stream>>>(Qw, Kw, Vt, Obf);
  k_gemm_out<<<640, 256, 0, stream>>>(Obf, Wdt, b_dense, (float*)d_out, 4096, 2560, 2560);
}

// Round 13
// 422.550 us; speedup vs baseline: 4.5815x; 1.0275x over previous
//
#include <hip/hip_runtime.h>

#define S_LEN 2048
#define NHEAD 32
#define HD 80
#define DPAD 96
#define HIDDEN 2560
#define QKV_N 7680

typedef __attribute__((ext_vector_type(8))) short bf16x8;
typedef __attribute__((ext_vector_type(8))) unsigned short u16x8;
typedef __attribute__((ext_vector_type(4))) float f32x4;

__device__ __forceinline__ unsigned short f2bf(float f) {
  unsigned int u = __float_as_uint(f);
  u += 0x7fffu + ((u >> 16) & 1u);   // RNE
  return (unsigned short)(u >> 16);
}
__device__ __forceinline__ float bf2f(unsigned short h) {
  return __uint_as_float(((unsigned int)h) << 16);
}

__device__ __forceinline__ void gload16(const void* g, void* l) {
  __builtin_amdgcn_global_load_lds((const __attribute__((address_space(1))) void*)g,
                                   (__attribute__((address_space(3))) void*)l, 16, 0, 0);
}

// ---------------- fp32 -> bf16 elementwise ----------------
__global__ __launch_bounds__(256) void k_cvt(const float* __restrict__ in,
                                             unsigned short* __restrict__ out, int n4) {
  int i = blockIdx.x * 256 + threadIdx.x;
  if (i >= n4) return;
  float4 v = reinterpret_cast<const float4*>(in)[i];
  ushort4 o;
  o.x = f2bf(v.x); o.y = f2bf(v.y); o.z = f2bf(v.z); o.w = f2bf(v.w);
  reinterpret_cast<ushort4*>(out)[i] = o;
}

// ---------------- fp32 (R x C) -> bf16 transposed (C x R), vectorized -------
__global__ __launch_bounds__(256) void k_transpose_bf16(const float* __restrict__ in,
                                                        unsigned short* __restrict__ out,
                                                        int R, int C) {
  __shared__ float tile[64][68];
  int tc = blockIdx.x * 64, tr = blockIdx.y * 64;
  for (int i = threadIdx.x; i < 64 * 16; i += 256) {
    int r = i >> 4, c4 = i & 15;
    float4 v = *(const float4*)&in[(size_t)(tr + r) * C + tc + c4 * 4];
    *(float4*)&tile[r][c4 * 4] = v;
  }
  __syncthreads();
  for (int i = threadIdx.x; i < 8 * 64; i += 256) {
    int ro = i >> 6, c = i & 63;
    u16x8 v;
#pragma unroll
    for (int j = 0; j < 8; ++j) v[j] = f2bf(tile[ro * 8 + j][c]);
    *(u16x8*)&out[(size_t)(tc + c) * R + tr + ro * 8] = v;
  }
}

// ---------------- gemm1 (QKV): 256x256, BK=32, R10-exact structure ----------
// NOTE: 128-VGPR accumulator => max 2 waves/EU (R11 spill lesson).
__global__ __launch_bounds__(512, 2)
void k_gemm_qkv(const unsigned short* __restrict__ A,
                const unsigned short* __restrict__ Bt,
                const float* __restrict__ bias,
                unsigned short* __restrict__ Cbf,
                int M, int N, int K) {
  __shared__ unsigned short sA[4][8192];
  __shared__ unsigned short sB[4][8192];
  const int nbn = N >> 8;
  const int nwg = (M >> 8) * nbn;
  int wg = blockIdx.x;
  const int cpx = nwg >> 3;          // nwg % 8 == 0
  wg = (wg & 7) * cpx + (wg >> 3);
  const int bm = wg / nbn, bn = wg - bm * nbn;
  const int tid = threadIdx.x;
  const int lane = tid & 63, wave = tid >> 6;
  const int wr = wave >> 2, wc = wave & 3;
  const int lc = lane & 15, lr = lane >> 4;

  const int sub = (lane & 7) ^ (lane >> 3);
  const int rstage = wave * 16 + ((lane >> 3) << 1) + (sub >> 2);
  const int cstage = (sub & 3) * 8;
  const unsigned short* Agp = A + (size_t)(bm * 256 + rstage) * K + cstage;
  const unsigned short* Bgp = Bt + (size_t)(bn * 256 + rstage) * K + cstage;
  const size_t halfoff = (size_t)128 * K;

  const int loff = ((lc >> 1) << 7) + (((((lc & 1) << 2) | lr) ^ (lc >> 1)) << 4);

  f32x4 acc[8][4];
  const f32x4 zero = {0.f, 0.f, 0.f, 0.f};
#pragma unroll
  for (int m = 0; m < 8; ++m)
#pragma unroll
    for (int n = 0; n < 4; ++n) acc[m][n] = zero;

  auto stage = [&](int buf, int t) {
    gload16(Agp + t * 32, &sA[buf][wave * 512]);
    gload16(Agp + halfoff + t * 32, &sA[buf][4096 + wave * 512]);
    gload16(Bgp + t * 32, &sB[buf][wave * 512]);
    gload16(Bgp + halfoff + t * 32, &sB[buf][4096 + wave * 512]);
  };

  const int NT = K >> 5;   // 80
#pragma unroll
  for (int t = 0; t < 3; ++t) stage(t, t);

  const int nj = NT >> 2;
  for (int j = 0; j < nj; ++j) {
#pragma unroll
    for (int to = 0; to < 4; ++to) {
      const int t = (j << 2) + to;
      if (t < NT - 2)       asm volatile("s_waitcnt vmcnt(8)" ::: "memory");
      else if (t == NT - 2) asm volatile("s_waitcnt vmcnt(4)" ::: "memory");
      else                  asm volatile("s_waitcnt vmcnt(0)" ::: "memory");
      __builtin_amdgcn_s_barrier();
      asm volatile("" ::: "memory");

      const char* bufA = (const char*)&sA[to][0];
      const char* bufB = (const char*)&sB[to][0];
      bf16x8 af[8], bfr[4];
#pragma unroll
      for (int mi = 0; mi < 8; ++mi)
        af[mi] = *(const bf16x8*)(bufA + ((wr * 128 + mi * 16) << 6) + loff);
#pragma unroll
      for (int ni = 0; ni < 4; ++ni)
        bfr[ni] = *(const bf16x8*)(bufB + ((wc * 64 + ni * 16) << 6) + loff);

      if (t + 3 < NT) stage((to + 3) & 3, t + 3);

      asm volatile("s_waitcnt lgkmcnt(0)" ::: "memory");
      __builtin_amdgcn_sched_barrier(0);
      __builtin_amdgcn_s_setprio(1);
#pragma unroll
      for (int mi = 0; mi < 8; ++mi)
#pragma unroll
        for (int ni = 0; ni < 4; ++ni)
          acc[mi][ni] = __builtin_amdgcn_mfma_f32_16x16x32_bf16(af[mi], bfr[ni], acc[mi][ni], 0, 0, 0);
      __builtin_amdgcn_s_setprio(0);
    }
  }

  const int rowb = bm * 256 + wr * 128;
  const int colb = bn * 256 + wc * 64;
#pragma unroll
  for (int ni = 0; ni < 4; ++ni) {
    const int col = colb + ni * 16 + lc;
    const float bv = bias[col];
#pragma unroll
    for (int mf = 0; mf < 8; ++mf) {
#pragma unroll
      for (int jj = 0; jj < 4; ++jj) {
        const int row = rowb + mf * 16 + lr * 4 + jj;
        Cbf[(size_t)row * N + col] = f2bf(acc[mf][ni][jj] + bv);
      }
    }
  }
}

// ---------------- gemm2 (out-proj): 128x128, 3-deep counted vmcnt -----------
// 4 waves, 48 KB LDS, __launch_bounds__(256,3) -> 3 blocks/CU, all 640
// resident.  Entry vmcnt(4) leaves tile t+1's loads in flight (never drains
// mid-loop); stage (t+2)%3 after frag reads of t%3 -- distinct from reading
// buf and in-flight buf (t+1)%3.
__global__ __launch_bounds__(256, 3)
void k_gemm_out(const unsigned short* __restrict__ A,
                const unsigned short* __restrict__ Bt,
                const float* __restrict__ bias,
                float* __restrict__ Cf,
                int M, int N, int K) {
  __shared__ unsigned short sA[3][4096];
  __shared__ unsigned short sB[3][4096];
  const int nbn = N >> 7;            // 20
  const int nwg = (M >> 7) * nbn;    // 640, % 8 == 0
  int wg = blockIdx.x;
  const int cpx = nwg >> 3;
  wg = (wg & 7) * cpx + (wg >> 3);
  const int bm = wg / nbn, bn = wg - bm * nbn;
  const int tid = threadIdx.x;
  const int lane = tid & 63, wave = tid >> 6;
  const int wr = wave >> 1, wc = wave & 1;
  const int lc = lane & 15, lr = lane >> 4;

  const int sub = (lane & 7) ^ (lane >> 3);
  const int rstage = wave * 16 + ((lane >> 3) << 1) + (sub >> 2);
  const int cstage = (sub & 3) * 8;
  const unsigned short* Agp = A + (size_t)(bm * 128 + rstage) * K + cstage;
  const unsigned short* Bgp = Bt + (size_t)(bn * 128 + rstage) * K + cstage;
  const size_t halfoff = (size_t)64 * K;

  const int loff = ((lc >> 1) << 7) + (((((lc & 1) << 2) | lr) ^ (lc >> 1)) << 4);

  f32x4 acc[4][4];
  const f32x4 zero = {0.f, 0.f, 0.f, 0.f};
#pragma unroll
  for (int m = 0; m < 4; ++m)
#pragma unroll
    for (int n = 0; n < 4; ++n) acc[m][n] = zero;

  auto stage = [&](int buf, int t) {
    gload16(Agp + t * 32, &sA[buf][wave * 512]);
    gload16(Agp + halfoff + t * 32, &sA[buf][2048 + wave * 512]);
    gload16(Bgp + t * 32, &sB[buf][wave * 512]);
    gload16(Bgp + halfoff + t * 32, &sB[buf][2048 + wave * 512]);
  };

  const int NT = K >> 5;   // 80
  stage(0, 0);
  stage(1, 1);
  int b0 = 0;
  for (int t = 0; t < NT; ++t) {
    if (t < NT - 1) asm volatile("s_waitcnt vmcnt(4)" ::: "memory");
    else            asm volatile("s_waitcnt vmcnt(0)" ::: "memory");
    __builtin_amdgcn_s_barrier();
    asm volatile("" ::: "memory");

    const char* bufA = (const char*)&sA[b0][0];
    const char* bufB = (const char*)&sB[b0][0];
    bf16x8 af[4], bfr[4];
#pragma unroll
    for (int mi = 0; mi < 4; ++mi)
      af[mi] = *(const bf16x8*)(bufA + ((wr * 64 + mi * 16) << 6) + loff);
#pragma unroll
    for (int ni = 0; ni < 4; ++ni)
      bfr[ni] = *(const bf16x8*)(bufB + ((wc * 64 + ni * 16) << 6) + loff);

    if (t + 2 < NT) {
      int bs = b0 - 1; if (bs < 0) bs = 2;   // (t+2)%3
      stage(bs, t + 2);
    }

    asm volatile("s_waitcnt lgkmcnt(0)" ::: "memory");
    __builtin_amdgcn_sched_barrier(0);
    __builtin_amdgcn_s_setprio(1);
#pragma unroll
    for (int mi = 0; mi < 4; ++mi)
#pragma unroll
      for (int ni = 0; ni < 4; ++ni)
        acc[mi][ni] = __builtin_amdgcn_mfma_f32_16x16x32_bf16(af[mi], bfr[ni], acc[mi][ni], 0, 0, 0);
    __builtin_amdgcn_s_setprio(0);
    ++b0; if (b0 == 3) b0 = 0;
  }

  const int rowb = bm * 128 + wr * 64;
  const int colb = bn * 128 + wc * 64;
#pragma unroll
  for (int ni = 0; ni < 4; ++ni) {
    const int col = colb + ni * 16 + lc;
    const float bv = bias[col];
#pragma unroll
    for (int mf = 0; mf < 4; ++mf) {
#pragma unroll
      for (int jj = 0; jj < 4; ++jj) {
        const int row = rowb + mf * 16 + lr * 4 + jj;
        Cf[(size_t)row * N + col] = acc[mf][ni][jj] + bv;
      }
    }
  }
}

// ---------------- RoPE + head split: qkv -> Q (scaled), K, V^T --------------
// Coalesced: octet index varies fastest across lanes (contiguous 192B row
// segments for Q/K, 160B for V).  Vector u16x8 loads/stores.
__global__ __launch_bounds__(256) void k_rope(const unsigned short* __restrict__ qkv,
                                              unsigned short* __restrict__ Qw,
                                              unsigned short* __restrict__ Kw,
                                              unsigned short* __restrict__ Vt) {
  const int blk = blockIdx.x;
  const int sc = blk & 31;
  const int bh = blk >> 5;
  const int b = bh >> 5, h = bh & 31;
  const int s0 = sc * 64;
  __shared__ float cs0[64][16], sn0[64][16];
  __shared__ unsigned short vbuf[64][88];
  const int tid = threadIdx.x;
  for (int i = tid; i < 64 * 16; i += 256) {
    int sl = i >> 4, fi = i & 15;
    float ang = (float)(s0 + sl) * __expf(-(float)fi * 0.575646273248511421f);
    cs0[sl][fi] = cosf(ang);
    sn0[sl][fi] = sinf(ang);
  }
  const size_t row0 = (size_t)(b * S_LEN + s0) * QKV_N;
  // V: 64 rows x 10 octets; o fastest -> coalesced
  for (int i = tid; i < 64 * 10; i += 256) {
    int sl = i / 10, o = i - sl * 10;
    *(u16x8*)&vbuf[sl][o * 8] =
        *(const u16x8*)&qkv[row0 + (size_t)sl * QKV_N + 2 * HIDDEN + h * HD + o * 8];
  }
  __syncthreads();
  // Q/K rope: 64 rows x 12 octets (o>=10 -> zero pad); o fastest -> coalesced
  const size_t obase = ((size_t)bh * S_LEN + s0) * DPAD;
  const float SCALE = 0.111803398874989485f;  // 80^-0.5
  for (int i = tid; i < 64 * 12; i += 256) {
    int sl = i / 12, o = i - sl * 12;
    u16x8 outq = {0, 0, 0, 0, 0, 0, 0, 0};
    u16x8 outk = {0, 0, 0, 0, 0, 0, 0, 0};
    if (o < 10) {
      const unsigned short* rp = qkv + row0 + (size_t)sl * QKV_N + h * HD;
      u16x8 xq = *(const u16x8*)(rp + o * 8);
      u16x8 xk = *(const u16x8*)(rp + HIDDEN + o * 8);
      if (o < 2) {
        u16x8 yq = *(const u16x8*)(rp + (o + 2) * 8);
        u16x8 yk = *(const u16x8*)(rp + HIDDEN + (o + 2) * 8);
#pragma unroll
        for (int j = 0; j < 8; ++j) {
          float c = cs0[sl][o * 8 + j], s = sn0[sl][o * 8 + j];
          outq[j] = f2bf((bf2f(xq[j]) * c - bf2f(yq[j]) * s) * SCALE);
          outk[j] = f2bf(bf2f(xk[j]) * c - bf2f(yk[j]) * s);
        }
      } else if (o < 4) {
        u16x8 yq = *(const u16x8*)(rp + (o - 2) * 8);
        u16x8 yk = *(const u16x8*)(rp + HIDDEN + (o - 2) * 8);
#pragma unroll
        for (int j = 0; j < 8; ++j) {
          float c = cs0[sl][(o - 2) * 8 + j], s = sn0[sl][(o - 2) * 8 + j];
          outq[j] = f2bf((bf2f(xq[j]) * c + bf2f(yq[j]) * s) * SCALE);
          outk[j] = f2bf(bf2f(xk[j]) * c + bf2f(yk[j]) * s);
        }
      } else {
#pragma unroll
        for (int j = 0; j < 8; ++j) {
          outq[j] = f2bf(bf2f(xq[j]) * SCALE);
          outk[j] = xk[j];
        }
      }
    }
    *(u16x8*)&Qw[obase + (size_t)sl * DPAD + o * 8] = outq;
    *(u16x8*)&Kw[obase + (size_t)sl * DPAD + o * 8] = outk;
  }
  // V^T: only rows d<80 (d>=80 never read by attn)
  const size_t vtb = (size_t)bh * DPAD * S_LEN + s0;
  for (int i = tid; i < 80 * 8; i += 256) {
    int d = i >> 3, so = i & 7;
    u16x8 v;
#pragma unroll
    for (int j = 0; j < 8; ++j) v[j] = vbuf[so * 8 + j][d];
    *(u16x8*)&Vt[vtb + (size_t)d * S_LEN + so * 8] = v;
  }
}

// ---------------- flash attention (causal), QBLK=128, KVBLK=64 ----------------
__global__ __launch_bounds__(256, 2) void k_attn(const unsigned short* __restrict__ Qw,
                                                 const unsigned short* __restrict__ Kw,
                                                 const unsigned short* __restrict__ Vt,
                                                 unsigned short* __restrict__ O) {
  __shared__ unsigned short sK[2][64 * 104];
  __shared__ unsigned short sV[2][80 * 72];
  __shared__ unsigned short sP[4][16 * 72];
  const int p = blockIdx.x;
  const int bh = blockIdx.y;
  const int b = bh >> 5, h = bh & 31;
  const int tid = threadIdx.x;
  const int wave = tid >> 6, lane = tid & 63;
  const int lr = lane >> 4, lc = lane & 15;
  unsigned short* Pw = &sP[wave][0];

  const unsigned short* Kh = Kw + (size_t)bh * S_LEN * DPAD;
  const unsigned short* Vh = Vt + (size_t)bh * DPAD * S_LEN;
  const unsigned short* Qh = Qw + (size_t)bh * S_LEN * DPAD;

  const int kr = tid >> 2, kc = (tid & 3) * 24;
  const int vr = tid >> 3, vc = (tid & 7) * 8;

  u16x8 kst0, kst1, kst2, vst0, vst1, vst2;
  auto gload = [&](int t) {
    const unsigned short* Kg = Kh + ((size_t)(t * 64 + kr)) * DPAD + kc;
    kst0 = *(const u16x8*)(Kg);
    kst1 = *(const u16x8*)(Kg + 8);
    kst2 = *(const u16x8*)(Kg + 16);
    const unsigned short* Vg = Vh + (size_t)vr * S_LEN + t * 64 + vc;
    vst0 = *(const u16x8*)(Vg);
    vst1 = *(const u16x8*)(Vg + 32 * S_LEN);
    if (tid < 128) vst2 = *(const u16x8*)(Vg + (size_t)64 * S_LEN);
  };
  auto swrite = [&](int buf) {
    *(u16x8*)&sK[buf][kr * 104 + kc] = kst0;
    *(u16x8*)&sK[buf][kr * 104 + kc + 8] = kst1;
    *(u16x8*)&sK[buf][kr * 104 + kc + 16] = kst2;
    *(u16x8*)&sV[buf][vr * 72 + vc] = vst0;
    *(u16x8*)&sV[buf][(vr + 32) * 72 + vc] = vst1;
    if (tid < 128) *(u16x8*)&sV[buf][(vr + 64) * 72 + vc] = vst2;
  };

  const f32x4 zero = {0.f, 0.f, 0.f, 0.f};

#pragma unroll 1
  for (int qi = 0; qi < 2; ++qi) {
    const int qt = qi ? (15 - p) : p;
    const int nt = 2 * qt + 2;
    const int wbase = qt * 128 + wave * 32;

    bf16x8 qf[2][3];
#pragma unroll
    for (int m = 0; m < 2; ++m)
#pragma unroll
      for (int ks = 0; ks < 3; ++ks)
        qf[m][ks] = *(const bf16x8*)&Qh[(size_t)(wbase + m * 16 + lc) * DPAD + ks * 32 + lr * 8];

    f32x4 oacc[2][5];
#pragma unroll
    for (int m = 0; m < 2; ++m)
#pragma unroll
      for (int n = 0; n < 5; ++n) oacc[m][n] = zero;
    float mrun[2] = {-1e30f, -1e30f}, lrun[2] = {0.f, 0.f};

    gload(0);
    __syncthreads();
    swrite(0);
    int cur = 0;

#pragma unroll 1
    for (int t = 0; t < nt; ++t) {
      __syncthreads();
      if (t + 1 < nt) gload(t + 1);
      const int ktb = t * 64;
      const bool act0 = ktb <= wbase + 15;
      const bool act1 = ktb <= wbase + 31;
      if (act1) {
        const unsigned short* Kc = sK[cur];
        const unsigned short* Vc = sV[cur];
        f32x4 sf[2][4];
#pragma unroll
        for (int n = 0; n < 4; ++n) {
          sf[0][n] = zero; sf[1][n] = zero;
#pragma unroll
          for (int ks = 0; ks < 3; ++ks) {
            bf16x8 kf = *(const bf16x8*)&Kc[(n * 16 + lc) * 104 + ks * 32 + lr * 8];
            if (act0) sf[0][n] = __builtin_amdgcn_mfma_f32_16x16x32_bf16(kf, qf[0][ks], sf[0][n], 0, 0, 0);
            sf[1][n] = __builtin_amdgcn_mfma_f32_16x16x32_bf16(kf, qf[1][ks], sf[1][n], 0, 0, 0);
          }
        }
        bf16x8 vf[5][2];
#pragma unroll
        for (int n = 0; n < 5; ++n)
#pragma unroll
          for (int ks = 0; ks < 2; ++ks)
            vf[n][ks] = *(const bf16x8*)&Vc[(n * 16 + lc) * 72 + ks * 32 + lr * 8];
#pragma unroll
        for (int m = 0; m < 2; ++m) {
          if (m == 0 && !act0) continue;
          const int qrow0 = wbase + m * 16;
          if (ktb + 63 > qrow0) {
#pragma unroll
            for (int n = 0; n < 4; ++n)
#pragma unroll
              for (int j = 0; j < 4; ++j)
                if (ktb + n * 16 + lr * 4 + j > qrow0 + lc) sf[m][n][j] = -1e30f;
          }
          float t0 = sf[m][0][0];
#pragma unroll
          for (int n = 0; n < 4; ++n)
#pragma unroll
            for (int j = 0; j < 4; ++j) t0 = fmaxf(t0, sf[m][n][j]);
          t0 = fmaxf(t0, __shfl_xor(t0, 16));
          t0 = fmaxf(t0, __shfl_xor(t0, 32));
          const float nm = fmaxf(mrun[m], t0);
          const float corrq = __expf(mrun[m] - nm);
          mrun[m] = nm;
          float ps = 0.f;
#pragma unroll
          for (int n = 0; n < 4; ++n)
#pragma unroll
            for (int j = 0; j < 4; ++j) {
              float e = __expf(sf[m][n][j] - nm);
              sf[m][n][j] = e;
              ps += e;
            }
          ps += __shfl_xor(ps, 16);
          ps += __shfl_xor(ps, 32);
          lrun[m] = lrun[m] * corrq + ps;
          float cj[4];
#pragma unroll
          for (int j = 0; j < 4; ++j) cj[j] = __shfl(corrq, lr * 4 + j, 16);
#pragma unroll
          for (int n = 0; n < 5; ++n)
#pragma unroll
            for (int j = 0; j < 4; ++j) oacc[m][n][j] *= cj[j];
#pragma unroll
          for (int n = 0; n < 4; ++n) {
            unsigned lo = (unsigned)f2bf(sf[m][n][0]) | ((unsigned)f2bf(sf[m][n][1]) << 16);
            unsigned hi = (unsigned)f2bf(sf[m][n][2]) | ((unsigned)f2bf(sf[m][n][3]) << 16);
            uint2 u; u.x = lo; u.y = hi;
            *(uint2*)&Pw[lc * 72 + n * 16 + lr * 4] = u;
          }
          asm volatile("" ::: "memory");
          bf16x8 pa0 = *(const bf16x8*)&Pw[lc * 72 + lr * 8];
          bf16x8 pa1 = *(const bf16x8*)&Pw[lc * 72 + 32 + lr * 8];
#pragma unroll
          for (int n = 0; n < 5; ++n) {
            oacc[m][n] = __builtin_amdgcn_mfma_f32_16x16x32_bf16(pa0, vf[n][0], oacc[m][n], 0, 0, 0);
            oacc[m][n] = __builtin_amdgcn_mfma_f32_16x16x32_bf16(pa1, vf[n][1], oacc[m][n], 0, 0, 0);
          }
          asm volatile("" ::: "memory");
        }
      }
      if (t + 1 < nt) swrite(cur ^ 1);
      cur ^= 1;
    }

#pragma unroll
    for (int m = 0; m < 2; ++m) {
      float linv[4];
#pragma unroll
      for (int j = 0; j < 4; ++j) {
        float lj = __shfl(lrun[m], lr * 4 + j, 16);
        linv[j] = 1.f / lj;
      }
      const int q0 = wbase + m * 16 + lr * 4;
#pragma unroll
      for (int n = 0; n < 5; ++n) {
        const int d = n * 16 + lc;
#pragma unroll
        for (int j = 0; j < 4; ++j)
          O[((size_t)(b * S_LEN) + q0 + j) * HIDDEN + h * HD + d] = f2bf(oacc[m][n][j] * linv[j]);
      }
    }
  }
}

extern "C" void kernel_launch(void* const* d_in, const int* in_sizes, int n_in,
                              void* d_out, int out_size, void* d_ws, size_t ws_size,
                              hipStream_t stream) {
  (void)in_sizes; (void)n_in; (void)out_size; (void)ws_size;
  const float* hidden  = (const float*)d_in[1];
  const float* w_qkv   = (const float*)d_in[2];
  const float* b_qkv   = (const float*)d_in[3];
  const float* w_dense = (const float*)d_in[4];
  const float* b_dense = (const float*)d_in[5];
  char* ws = (char*)d_ws;
  unsigned short* Abf   = (unsigned short*)(ws + 0);          // 4096x2560 bf16
  unsigned short* Wqkvt = (unsigned short*)(ws + 20971520);   // 7680x2560 bf16
  unsigned short* Wdt   = (unsigned short*)(ws + 60293120);   // 2560x2560 bf16
  unsigned short* QKVb  = (unsigned short*)(ws + 73400320);   // 4096x7680 bf16
  unsigned short* Qw    = (unsigned short*)(ws + 136314880);  // 64x2048x96 bf16
  unsigned short* Kw    = (unsigned short*)(ws + 161480704);
  unsigned short* Vt    = (unsigned short*)(ws + 186646528);
  unsigned short* Obf   = (unsigned short*)(ws + 211812352);  // 4096x2560 bf16

  k_cvt<<<10240, 256, 0, stream>>>(hidden, Abf, 2621440);
  k_transpose_bf16<<<dim3(120, 40), 256, 0, stream>>>(w_qkv, Wqkvt, 2560, 7680);
  k_transpose_bf16<<<dim3(40, 40), 256, 0, stream>>>(w_dense, Wdt, 2560, 2560);
  k_gemm_qkv<<<480, 512, 0, stream>>>(Abf, Wqkvt, b_qkv, QKVb, 4096, 7680, 2560);
  k_rope<<<2048, 256, 0, stream>>>(QKVb, Qw, Kw, Vt);
  k_attn<<<dim3(8, 64), 256, 0, stream>>>(Qw, Kw, Vt, Obf);
  k_gemm_out<<<640, 256, 0, stream>>>(Obf, Wdt, b_dense, (float*)d_out, 4096, 2560, 2560);
}

// Round 14
// 410.487 us; speedup vs baseline: 4.7161x; 1.0294x over previous
//
#include <hip/hip_runtime.h>

#define S_LEN 2048
#define NHEAD 32
#define HD 80
#define DPAD 96
#define HIDDEN 2560
#define QKV_N 7680

typedef __attribute__((ext_vector_type(8))) short bf16x8;
typedef __attribute__((ext_vector_type(8))) unsigned short u16x8;
typedef __attribute__((ext_vector_type(4))) float f32x4;

__device__ __forceinline__ unsigned short f2bf(float f) {
  unsigned int u = __float_as_uint(f);
  u += 0x7fffu + ((u >> 16) & 1u);   // RNE
  return (unsigned short)(u >> 16);
}
__device__ __forceinline__ float bf2f(unsigned short h) {
  return __uint_as_float(((unsigned int)h) << 16);
}

__device__ __forceinline__ void gload16(const void* g, void* l) {
  __builtin_amdgcn_global_load_lds((const __attribute__((address_space(1))) void*)g,
                                   (__attribute__((address_space(3))) void*)l, 16, 0, 0);
}

// ---------------- fp32 -> bf16 elementwise ----------------
__global__ __launch_bounds__(256) void k_cvt(const float* __restrict__ in,
                                             unsigned short* __restrict__ out, int n4) {
  int i = blockIdx.x * 256 + threadIdx.x;
  if (i >= n4) return;
  float4 v = reinterpret_cast<const float4*>(in)[i];
  ushort4 o;
  o.x = f2bf(v.x); o.y = f2bf(v.y); o.z = f2bf(v.z); o.w = f2bf(v.w);
  reinterpret_cast<ushort4*>(out)[i] = o;
}

// ---------------- fp32 (R x C) -> bf16 transposed (C x R), vectorized -------
__global__ __launch_bounds__(256) void k_transpose_bf16(const float* __restrict__ in,
                                                        unsigned short* __restrict__ out,
                                                        int R, int C) {
  __shared__ float tile[64][68];
  int tc = blockIdx.x * 64, tr = blockIdx.y * 64;
  for (int i = threadIdx.x; i < 64 * 16; i += 256) {
    int r = i >> 4, c4 = i & 15;
    float4 v = *(const float4*)&in[(size_t)(tr + r) * C + tc + c4 * 4];
    *(float4*)&tile[r][c4 * 4] = v;
  }
  __syncthreads();
  for (int i = threadIdx.x; i < 8 * 64; i += 256) {
    int ro = i >> 6, c = i & 63;
    u16x8 v;
#pragma unroll
    for (int j = 0; j < 8; ++j) v[j] = f2bf(tile[ro * 8 + j][c]);
    *(u16x8*)&out[(size_t)(tc + c) * R + tr + ro * 8] = v;
  }
}

// ---------------- gemm1 (QKV): 256x256, BK=32, R10 structure + 2D XCD chunks
// Each XCD gets a 4bm x 15bn chunk (A 5.2MB + B 19.7MB per XCD) instead of
// 2bm x 30bn (B 39.3MB per XCD) -> predicted FETCH 312 -> ~205 MB.
// NOTE: 128-VGPR accumulator => max 2 waves/EU (R11 spill lesson).
__global__ __launch_bounds__(512, 2)
void k_gemm_qkv(const unsigned short* __restrict__ A,
                const unsigned short* __restrict__ Bt,
                const float* __restrict__ bias,
                unsigned short* __restrict__ Cbf,
                int M, int N, int K) {
  __shared__ unsigned short sA[4][8192];
  __shared__ unsigned short sB[4][8192];
  const int nbm = M >> 8, nbn = N >> 8;
  // 2D XCD chunking: chunks of (nbm/4) x (nbn/2); requires nbm%4==0, nbn%2==0
  const int CM = nbm >> 2, CN = nbn >> 1;
  {
    // fold blockIdx into (bm,bn) below
  }
  int wg = blockIdx.x;
  const int xcd = wg & 7;
  const int idx = wg >> 3;                 // 0 .. CM*CN-1
  const int bm = (xcd >> 1) * CM + idx / CN;
  const int bn = (xcd & 1) * CN + idx % CN;
  const int tid = threadIdx.x;
  const int lane = tid & 63, wave = tid >> 6;
  const int wr = wave >> 2, wc = wave & 3;
  const int lc = lane & 15, lr = lane >> 4;

  const int sub = (lane & 7) ^ (lane >> 3);
  const int rstage = wave * 16 + ((lane >> 3) << 1) + (sub >> 2);
  const int cstage = (sub & 3) * 8;
  const unsigned short* Agp = A + (size_t)(bm * 256 + rstage) * K + cstage;
  const unsigned short* Bgp = Bt + (size_t)(bn * 256 + rstage) * K + cstage;
  const size_t halfoff = (size_t)128 * K;

  const int loff = ((lc >> 1) << 7) + (((((lc & 1) << 2) | lr) ^ (lc >> 1)) << 4);

  f32x4 acc[8][4];
  const f32x4 zero = {0.f, 0.f, 0.f, 0.f};
#pragma unroll
  for (int m = 0; m < 8; ++m)
#pragma unroll
    for (int n = 0; n < 4; ++n) acc[m][n] = zero;

  auto stage = [&](int buf, int t) {
    gload16(Agp + t * 32, &sA[buf][wave * 512]);
    gload16(Agp + halfoff + t * 32, &sA[buf][4096 + wave * 512]);
    gload16(Bgp + t * 32, &sB[buf][wave * 512]);
    gload16(Bgp + halfoff + t * 32, &sB[buf][4096 + wave * 512]);
  };

  const int NT = K >> 5;   // 80
#pragma unroll
  for (int t = 0; t < 3; ++t) stage(t, t);

  const int nj = NT >> 2;
  for (int j = 0; j < nj; ++j) {
#pragma unroll
    for (int to = 0; to < 4; ++to) {
      const int t = (j << 2) + to;
      if (t < NT - 2)       asm volatile("s_waitcnt vmcnt(8)" ::: "memory");
      else if (t == NT - 2) asm volatile("s_waitcnt vmcnt(4)" ::: "memory");
      else                  asm volatile("s_waitcnt vmcnt(0)" ::: "memory");
      __builtin_amdgcn_s_barrier();
      asm volatile("" ::: "memory");

      const char* bufA = (const char*)&sA[to][0];
      const char* bufB = (const char*)&sB[to][0];
      bf16x8 af[8], bfr[4];
#pragma unroll
      for (int mi = 0; mi < 8; ++mi)
        af[mi] = *(const bf16x8*)(bufA + ((wr * 128 + mi * 16) << 6) + loff);
#pragma unroll
      for (int ni = 0; ni < 4; ++ni)
        bfr[ni] = *(const bf16x8*)(bufB + ((wc * 64 + ni * 16) << 6) + loff);

      if (t + 3 < NT) stage((to + 3) & 3, t + 3);

      asm volatile("s_waitcnt lgkmcnt(0)" ::: "memory");
      __builtin_amdgcn_sched_barrier(0);
      __builtin_amdgcn_s_setprio(1);
#pragma unroll
      for (int mi = 0; mi < 8; ++mi)
#pragma unroll
        for (int ni = 0; ni < 4; ++ni)
          acc[mi][ni] = __builtin_amdgcn_mfma_f32_16x16x32_bf16(af[mi], bfr[ni], acc[mi][ni], 0, 0, 0);
      __builtin_amdgcn_s_setprio(0);
    }
  }

  const int rowb = bm * 256 + wr * 128;
  const int colb = bn * 256 + wc * 64;
#pragma unroll
  for (int ni = 0; ni < 4; ++ni) {
    const int col = colb + ni * 16 + lc;
    const float bv = bias[col];
#pragma unroll
    for (int mf = 0; mf < 8; ++mf) {
#pragma unroll
      for (int jj = 0; jj < 4; ++jj) {
        const int row = rowb + mf * 16 + lr * 4 + jj;
        Cbf[(size_t)row * N + col] = f2bf(acc[mf][ni][jj] + bv);
      }
    }
  }
}

// ---------------- gemm2 (out-proj): 128x128, 3-deep counted vmcnt + 2D XCD --
__global__ __launch_bounds__(256, 3)
void k_gemm_out(const unsigned short* __restrict__ A,
                const unsigned short* __restrict__ Bt,
                const float* __restrict__ bias,
                float* __restrict__ Cf,
                int M, int N, int K) {
  __shared__ unsigned short sA[3][4096];
  __shared__ unsigned short sB[3][4096];
  const int nbm = M >> 7, nbn = N >> 7;     // 32, 20
  const int CM = nbm >> 2, CN = nbn >> 1;   // 8, 10
  int wg = blockIdx.x;
  const int xcd = wg & 7;
  const int idx = wg >> 3;
  const int bm = (xcd >> 1) * CM + idx / CN;
  const int bn = (xcd & 1) * CN + idx % CN;
  const int tid = threadIdx.x;
  const int lane = tid & 63, wave = tid >> 6;
  const int wr = wave >> 1, wc = wave & 1;
  const int lc = lane & 15, lr = lane >> 4;

  const int sub = (lane & 7) ^ (lane >> 3);
  const int rstage = wave * 16 + ((lane >> 3) << 1) + (sub >> 2);
  const int cstage = (sub & 3) * 8;
  const unsigned short* Agp = A + (size_t)(bm * 128 + rstage) * K + cstage;
  const unsigned short* Bgp = Bt + (size_t)(bn * 128 + rstage) * K + cstage;
  const size_t halfoff = (size_t)64 * K;

  const int loff = ((lc >> 1) << 7) + (((((lc & 1) << 2) | lr) ^ (lc >> 1)) << 4);

  f32x4 acc[4][4];
  const f32x4 zero = {0.f, 0.f, 0.f, 0.f};
#pragma unroll
  for (int m = 0; m < 4; ++m)
#pragma unroll
    for (int n = 0; n < 4; ++n) acc[m][n] = zero;

  auto stage = [&](int buf, int t) {
    gload16(Agp + t * 32, &sA[buf][wave * 512]);
    gload16(Agp + halfoff + t * 32, &sA[buf][2048 + wave * 512]);
    gload16(Bgp + t * 32, &sB[buf][wave * 512]);
    gload16(Bgp + halfoff + t * 32, &sB[buf][2048 + wave * 512]);
  };

  const int NT = K >> 5;   // 80
  stage(0, 0);
  stage(1, 1);
  int b0 = 0;
  for (int t = 0; t < NT; ++t) {
    if (t < NT - 1) asm volatile("s_waitcnt vmcnt(4)" ::: "memory");
    else            asm volatile("s_waitcnt vmcnt(0)" ::: "memory");
    __builtin_amdgcn_s_barrier();
    asm volatile("" ::: "memory");

    const char* bufA = (const char*)&sA[b0][0];
    const char* bufB = (const char*)&sB[b0][0];
    bf16x8 af[4], bfr[4];
#pragma unroll
    for (int mi = 0; mi < 4; ++mi)
      af[mi] = *(const bf16x8*)(bufA + ((wr * 64 + mi * 16) << 6) + loff);
#pragma unroll
    for (int ni = 0; ni < 4; ++ni)
      bfr[ni] = *(const bf16x8*)(bufB + ((wc * 64 + ni * 16) << 6) + loff);

    if (t + 2 < NT) {
      int bs = b0 - 1; if (bs < 0) bs = 2;   // (t+2)%3
      stage(bs, t + 2);
    }

    asm volatile("s_waitcnt lgkmcnt(0)" ::: "memory");
    __builtin_amdgcn_sched_barrier(0);
    __builtin_amdgcn_s_setprio(1);
#pragma unroll
    for (int mi = 0; mi < 4; ++mi)
#pragma unroll
      for (int ni = 0; ni < 4; ++ni)
        acc[mi][ni] = __builtin_amdgcn_mfma_f32_16x16x32_bf16(af[mi], bfr[ni], acc[mi][ni], 0, 0, 0);
    __builtin_amdgcn_s_setprio(0);
    ++b0; if (b0 == 3) b0 = 0;
  }

  const int rowb = bm * 128 + wr * 64;
  const int colb = bn * 128 + wc * 64;
#pragma unroll
  for (int ni = 0; ni < 4; ++ni) {
    const int col = colb + ni * 16 + lc;
    const float bv = bias[col];
#pragma unroll
    for (int mf = 0; mf < 4; ++mf) {
#pragma unroll
      for (int jj = 0; jj < 4; ++jj) {
        const int row = rowb + mf * 16 + lr * 4 + jj;
        Cf[(size_t)row * N + col] = acc[mf][ni][jj] + bv;
      }
    }
  }
}

// ---------------- RoPE + head split: qkv -> Q (scaled), K, V^T --------------
__global__ __launch_bounds__(256) void k_rope(const unsigned short* __restrict__ qkv,
                                              unsigned short* __restrict__ Qw,
                                              unsigned short* __restrict__ Kw,
                                              unsigned short* __restrict__ Vt) {
  const int blk = blockIdx.x;
  const int sc = blk & 31;
  const int bh = blk >> 5;
  const int b = bh >> 5, h = bh & 31;
  const int s0 = sc * 64;
  __shared__ float cs0[64][16], sn0[64][16];
  __shared__ unsigned short vbuf[64][88];
  const int tid = threadIdx.x;
  for (int i = tid; i < 64 * 16; i += 256) {
    int sl = i >> 4, fi = i & 15;
    float ang = (float)(s0 + sl) * __expf(-(float)fi * 0.575646273248511421f);
    cs0[sl][fi] = cosf(ang);
    sn0[sl][fi] = sinf(ang);
  }
  const size_t row0 = (size_t)(b * S_LEN + s0) * QKV_N;
  for (int i = tid; i < 64 * 10; i += 256) {
    int sl = i / 10, o = i - sl * 10;
    *(u16x8*)&vbuf[sl][o * 8] =
        *(const u16x8*)&qkv[row0 + (size_t)sl * QKV_N + 2 * HIDDEN + h * HD + o * 8];
  }
  __syncthreads();
  const size_t obase = ((size_t)bh * S_LEN + s0) * DPAD;
  const float SCALE = 0.111803398874989485f;  // 80^-0.5
  for (int i = tid; i < 64 * 12; i += 256) {
    int sl = i / 12, o = i - sl * 12;
    u16x8 outq = {0, 0, 0, 0, 0, 0, 0, 0};
    u16x8 outk = {0, 0, 0, 0, 0, 0, 0, 0};
    if (o < 10) {
      const unsigned short* rp = qkv + row0 + (size_t)sl * QKV_N + h * HD;
      u16x8 xq = *(const u16x8*)(rp + o * 8);
      u16x8 xk = *(const u16x8*)(rp + HIDDEN + o * 8);
      if (o < 2) {
        u16x8 yq = *(const u16x8*)(rp + (o + 2) * 8);
        u16x8 yk = *(const u16x8*)(rp + HIDDEN + (o + 2) * 8);
#pragma unroll
        for (int j = 0; j < 8; ++j) {
          float c = cs0[sl][o * 8 + j], s = sn0[sl][o * 8 + j];
          outq[j] = f2bf((bf2f(xq[j]) * c - bf2f(yq[j]) * s) * SCALE);
          outk[j] = f2bf(bf2f(xk[j]) * c - bf2f(yk[j]) * s);
        }
      } else if (o < 4) {
        u16x8 yq = *(const u16x8*)(rp + (o - 2) * 8);
        u16x8 yk = *(const u16x8*)(rp + HIDDEN + (o - 2) * 8);
#pragma unroll
        for (int j = 0; j < 8; ++j) {
          float c = cs0[sl][(o - 2) * 8 + j], s = sn0[sl][(o - 2) * 8 + j];
          outq[j] = f2bf((bf2f(xq[j]) * c + bf2f(yq[j]) * s) * SCALE);
          outk[j] = f2bf(bf2f(xk[j]) * c + bf2f(yk[j]) * s);
        }
      } else {
#pragma unroll
        for (int j = 0; j < 8; ++j) {
          outq[j] = f2bf(bf2f(xq[j]) * SCALE);
          outk[j] = xk[j];
        }
      }
    }
    *(u16x8*)&Qw[obase + (size_t)sl * DPAD + o * 8] = outq;
    *(u16x8*)&Kw[obase + (size_t)sl * DPAD + o * 8] = outk;
  }
  const size_t vtb = (size_t)bh * DPAD * S_LEN + s0;
  for (int i = tid; i < 80 * 8; i += 256) {
    int d = i >> 3, so = i & 7;
    u16x8 v;
#pragma unroll
    for (int j = 0; j < 8; ++j) v[j] = vbuf[so * 8 + j][d];
    *(u16x8*)&Vt[vtb + (size_t)d * S_LEN + so * 8] = v;
  }
}

// ---------------- flash attention (causal), QBLK=128, KVBLK=64 ----------------
__global__ __launch_bounds__(256, 2) void k_attn(const unsigned short* __restrict__ Qw,
                                                 const unsigned short* __restrict__ Kw,
                                                 const unsigned short* __restrict__ Vt,
                                                 unsigned short* __restrict__ O) {
  __shared__ unsigned short sK[2][64 * 104];
  __shared__ unsigned short sV[2][80 * 72];
  __shared__ unsigned short sP[4][16 * 72];
  const int p = blockIdx.x;
  const int bh = blockIdx.y;
  const int b = bh >> 5, h = bh & 31;
  const int tid = threadIdx.x;
  const int wave = tid >> 6, lane = tid & 63;
  const int lr = lane >> 4, lc = lane & 15;
  unsigned short* Pw = &sP[wave][0];

  const unsigned short* Kh = Kw + (size_t)bh * S_LEN * DPAD;
  const unsigned short* Vh = Vt + (size_t)bh * DPAD * S_LEN;
  const unsigned short* Qh = Qw + (size_t)bh * S_LEN * DPAD;

  const int kr = tid >> 2, kc = (tid & 3) * 24;
  const int vr = tid >> 3, vc = (tid & 7) * 8;

  u16x8 kst0, kst1, kst2, vst0, vst1, vst2;
  auto gload = [&](int t) {
    const unsigned short* Kg = Kh + ((size_t)(t * 64 + kr)) * DPAD + kc;
    kst0 = *(const u16x8*)(Kg);
    kst1 = *(const u16x8*)(Kg + 8);
    kst2 = *(const u16x8*)(Kg + 16);
    const unsigned short* Vg = Vh + (size_t)vr * S_LEN + t * 64 + vc;
    vst0 = *(const u16x8*)(Vg);
    vst1 = *(const u16x8*)(Vg + 32 * S_LEN);
    if (tid < 128) vst2 = *(const u16x8*)(Vg + (size_t)64 * S_LEN);
  };
  auto swrite = [&](int buf) {
    *(u16x8*)&sK[buf][kr * 104 + kc] = kst0;
    *(u16x8*)&sK[buf][kr * 104 + kc + 8] = kst1;
    *(u16x8*)&sK[buf][kr * 104 + kc + 16] = kst2;
    *(u16x8*)&sV[buf][vr * 72 + vc] = vst0;
    *(u16x8*)&sV[buf][(vr + 32) * 72 + vc] = vst1;
    if (tid < 128) *(u16x8*)&sV[buf][(vr + 64) * 72 + vc] = vst2;
  };

  const f32x4 zero = {0.f, 0.f, 0.f, 0.f};

#pragma unroll 1
  for (int qi = 0; qi < 2; ++qi) {
    const int qt = qi ? (15 - p) : p;
    const int nt = 2 * qt + 2;
    const int wbase = qt * 128 + wave * 32;

    bf16x8 qf[2][3];
#pragma unroll
    for (int m = 0; m < 2; ++m)
#pragma unroll
      for (int ks = 0; ks < 3; ++ks)
        qf[m][ks] = *(const bf16x8*)&Qh[(size_t)(wbase + m * 16 + lc) * DPAD + ks * 32 + lr * 8];

    f32x4 oacc[2][5];
#pragma unroll
    for (int m = 0; m < 2; ++m)
#pragma unroll
      for (int n = 0; n < 5; ++n) oacc[m][n] = zero;
    float mrun[2] = {-1e30f, -1e30f}, lrun[2] = {0.f, 0.f};

    gload(0);
    __syncthreads();
    swrite(0);
    int cur = 0;

#pragma unroll 1
    for (int t = 0; t < nt; ++t) {
      __syncthreads();
      if (t + 1 < nt) gload(t + 1);
      const int ktb = t * 64;
      const bool act0 = ktb <= wbase + 15;
      const bool act1 = ktb <= wbase + 31;
      if (act1) {
        const unsigned short* Kc = sK[cur];
        const unsigned short* Vc = sV[cur];
        f32x4 sf[2][4];
#pragma unroll
        for (int n = 0; n < 4; ++n) {
          sf[0][n] = zero; sf[1][n] = zero;
#pragma unroll
          for (int ks = 0; ks < 3; ++ks) {
            bf16x8 kf = *(const bf16x8*)&Kc[(n * 16 + lc) * 104 + ks * 32 + lr * 8];
            if (act0) sf[0][n] = __builtin_amdgcn_mfma_f32_16x16x32_bf16(kf, qf[0][ks], sf[0][n], 0, 0, 0);
            sf[1][n] = __builtin_amdgcn_mfma_f32_16x16x32_bf16(kf, qf[1][ks], sf[1][n], 0, 0, 0);
          }
        }
        bf16x8 vf[5][2];
#pragma unroll
        for (int n = 0; n < 5; ++n)
#pragma unroll
          for (int ks = 0; ks < 2; ++ks)
            vf[n][ks] = *(const bf16x8*)&Vc[(n * 16 + lc) * 72 + ks * 32 + lr * 8];
#pragma unroll
        for (int m = 0; m < 2; ++m) {
          if (m == 0 && !act0) continue;
          const int qrow0 = wbase + m * 16;
          if (ktb + 63 > qrow0) {
#pragma unroll
            for (int n = 0; n < 4; ++n)
#pragma unroll
              for (int j = 0; j < 4; ++j)
                if (ktb + n * 16 + lr * 4 + j > qrow0 + lc) sf[m][n][j] = -1e30f;
          }
          float t0 = sf[m][0][0];
#pragma unroll
          for (int n = 0; n < 4; ++n)
#pragma unroll
            for (int j = 0; j < 4; ++j) t0 = fmaxf(t0, sf[m][n][j]);
          t0 = fmaxf(t0, __shfl_xor(t0, 16));
          t0 = fmaxf(t0, __shfl_xor(t0, 32));
          const float nm = fmaxf(mrun[m], t0);
          const float corrq = __expf(mrun[m] - nm);
          mrun[m] = nm;
          float ps = 0.f;
#pragma unroll
          for (int n = 0; n < 4; ++n)
#pragma unroll
            for (int j = 0; j < 4; ++j) {
              float e = __expf(sf[m][n][j] - nm);
              sf[m][n][j] = e;
              ps += e;
            }
          ps += __shfl_xor(ps, 16);
          ps += __shfl_xor(ps, 32);
          lrun[m] = lrun[m] * corrq + ps;
          float cj[4];
#pragma unroll
          for (int j = 0; j < 4; ++j) cj[j] = __shfl(corrq, lr * 4 + j, 16);
#pragma unroll
          for (int n = 0; n < 5; ++n)
#pragma unroll
            for (int j = 0; j < 4; ++j) oacc[m][n][j] *= cj[j];
#pragma unroll
          for (int n = 0; n < 4; ++n) {
            unsigned lo = (unsigned)f2bf(sf[m][n][0]) | ((unsigned)f2bf(sf[m][n][1]) << 16);
            unsigned hi = (unsigned)f2bf(sf[m][n][2]) | ((unsigned)f2bf(sf[m][n][3]) << 16);
            uint2 u; u.x = lo; u.y = hi;
            *(uint2*)&Pw[lc * 72 + n * 16 + lr * 4] = u;
          }
          asm volatile("" ::: "memory");
          bf16x8 pa0 = *(const bf16x8*)&Pw[lc * 72 + lr * 8];
          bf16x8 pa1 = *(const bf16x8*)&Pw[lc * 72 + 32 + lr * 8];
#pragma unroll
          for (int n = 0; n < 5; ++n) {
            oacc[m][n] = __builtin_amdgcn_mfma_f32_16x16x32_bf16(pa0, vf[n][0], oacc[m][n], 0, 0, 0);
            oacc[m][n] = __builtin_amdgcn_mfma_f32_16x16x32_bf16(pa1, vf[n][1], oacc[m][n], 0, 0, 0);
          }
          asm volatile("" ::: "memory");
        }
      }
      if (t + 1 < nt) swrite(cur ^ 1);
      cur ^= 1;
    }

#pragma unroll
    for (int m = 0; m < 2; ++m) {
      float linv[4];
#pragma unroll
      for (int j = 0; j < 4; ++j) {
        float lj = __shfl(lrun[m], lr * 4 + j, 16);
        linv[j] = 1.f / lj;
      }
      const int q0 = wbase + m * 16 + lr * 4;
#pragma unroll
      for (int n = 0; n < 5; ++n) {
        const int d = n * 16 + lc;
#pragma unroll
        for (int j = 0; j < 4; ++j)
          O[((size_t)(b * S_LEN) + q0 + j) * HIDDEN + h * HD + d] = f2bf(oacc[m][n][j] * linv[j]);
      }
    }
  }
}

extern "C" void kernel_launch(void* const* d_in, const int* in_sizes, int n_in,
                              void* d_out, int out_size, void* d_ws, size_t ws_size,
                              hipStream_t stream) {
  (void)in_sizes; (void)n_in; (void)out_size; (void)ws_size;
  const float* hidden  = (const float*)d_in[1];
  const float* w_qkv   = (const float*)d_in[2];
  const float* b_qkv   = (const float*)d_in[3];
  const float* w_dense = (const float*)d_in[4];
  const float* b_dense = (const float*)d_in[5];
  char* ws = (char*)d_ws;
  unsigned short* Abf   = (unsigned short*)(ws + 0);          // 4096x2560 bf16
  unsigned short* Wqkvt = (unsigned short*)(ws + 20971520);   // 7680x2560 bf16
  unsigned short* Wdt   = (unsigned short*)(ws + 60293120);   // 2560x2560 bf16
  unsigned short* QKVb  = (unsigned short*)(ws + 73400320);   // 4096x7680 bf16
  unsigned short* Qw    = (unsigned short*)(ws + 136314880);  // 64x2048x96 bf16
  unsigned short* Kw    = (unsigned short*)(ws + 161480704);
  unsigned short* Vt    = (unsigned short*)(ws + 186646528);
  unsigned short* Obf   = (unsigned short*)(ws + 211812352);  // 4096x2560 bf16

  k_cvt<<<10240, 256, 0, stream>>>(hidden, Abf, 2621440);
  k_transpose_bf16<<<dim3(120, 40), 256, 0, stream>>>(w_qkv, Wqkvt, 2560, 7680);
  k_transpose_bf16<<<dim3(40, 40), 256, 0, stream>>>(w_dense, Wdt, 2560, 2560);
  k_gemm_qkv<<<480, 512, 0, stream>>>(Abf, Wqkvt, b_qkv, QKVb, 4096, 7680, 2560);
  k_rope<<<2048, 256, 0, stream>>>(QKVb, Qw, Kw, Vt);
  k_attn<<<dim3(8, 64), 256, 0, stream>>>(Qw, Kw, Vt, Obf);
  k_gemm_out<<<640, 256, 0, stream>>>(Obf, Wdt, b_dense, (float*)d_out, 4096, 2560, 2560);
}

// Round 15
// 403.243 us; speedup vs baseline: 4.8008x; 1.0180x over previous
//
#include <hip/hip_runtime.h>

#define S_LEN 2048
#define NHEAD 32
#define HD 80
#define DPAD 96
#define HIDDEN 2560
#define QKV_N 7680

typedef __attribute__((ext_vector_type(8))) short bf16x8;
typedef __attribute__((ext_vector_type(8))) unsigned short u16x8;
typedef __attribute__((ext_vector_type(4))) float f32x4;

__device__ __forceinline__ unsigned short f2bf(float f) {
  unsigned int u = __float_as_uint(f);
  u += 0x7fffu + ((u >> 16) & 1u);   // RNE
  return (unsigned short)(u >> 16);
}
__device__ __forceinline__ float bf2f(unsigned short h) {
  return __uint_as_float(((unsigned int)h) << 16);
}

__device__ __forceinline__ void gload16(const void* g, void* l) {
  __builtin_amdgcn_global_load_lds((const __attribute__((address_space(1))) void*)g,
                                   (__attribute__((address_space(3))) void*)l, 16, 0, 0);
}

// ---------------- fp32 -> bf16 elementwise ----------------
__global__ __launch_bounds__(256) void k_cvt(const float* __restrict__ in,
                                             unsigned short* __restrict__ out, int n4) {
  int i = blockIdx.x * 256 + threadIdx.x;
  if (i >= n4) return;
  float4 v = reinterpret_cast<const float4*>(in)[i];
  ushort4 o;
  o.x = f2bf(v.x); o.y = f2bf(v.y); o.z = f2bf(v.z); o.w = f2bf(v.w);
  reinterpret_cast<ushort4*>(out)[i] = o;
}

// ---------------- fp32 (R x C) -> bf16 transposed (C x R), vectorized -------
__global__ __launch_bounds__(256) void k_transpose_bf16(const float* __restrict__ in,
                                                        unsigned short* __restrict__ out,
                                                        int R, int C) {
  __shared__ float tile[64][68];
  int tc = blockIdx.x * 64, tr = blockIdx.y * 64;
  for (int i = threadIdx.x; i < 64 * 16; i += 256) {
    int r = i >> 4, c4 = i & 15;
    float4 v = *(const float4*)&in[(size_t)(tr + r) * C + tc + c4 * 4];
    *(float4*)&tile[r][c4 * 4] = v;
  }
  __syncthreads();
  for (int i = threadIdx.x; i < 8 * 64; i += 256) {
    int ro = i >> 6, c = i & 63;
    u16x8 v;
#pragma unroll
    for (int j = 0; j < 8; ++j) v[j] = f2bf(tile[ro * 8 + j][c]);
    *(u16x8*)&out[(size_t)(tc + c) * R + tr + ro * 8] = v;
  }
}

// ---------------- gemm1 (QKV): 256x256, BK=32, R10 structure + 2D XCD chunks
// Epilogue v2: per-wave LDS relayout -> coalesced u16x8 stores (fixes the
// 1.8x write amplification seen in R14: WRITE_SIZE 112MB vs 63MB ideal).
// NOTE: 128-VGPR accumulator => max 2 waves/EU (R11 spill lesson).
__global__ __launch_bounds__(512, 2)
void k_gemm_qkv(const unsigned short* __restrict__ A,
                const unsigned short* __restrict__ Bt,
                const float* __restrict__ bias,
                unsigned short* __restrict__ Cbf,
                int M, int N, int K) {
  __shared__ unsigned short sA[4][8192];
  __shared__ unsigned short sB[4][8192];
  const int nbm = M >> 8, nbn = N >> 8;
  const int CM = nbm >> 2, CN = nbn >> 1;   // 2D XCD chunks (4bm x 15bn)
  int wg = blockIdx.x;
  const int xcd = wg & 7;
  const int idx = wg >> 3;
  const int bm = (xcd >> 1) * CM + idx / CN;
  const int bn = (xcd & 1) * CN + idx % CN;
  const int tid = threadIdx.x;
  const int lane = tid & 63, wave = tid >> 6;
  const int wr = wave >> 2, wc = wave & 3;
  const int lc = lane & 15, lr = lane >> 4;

  const int sub = (lane & 7) ^ (lane >> 3);
  const int rstage = wave * 16 + ((lane >> 3) << 1) + (sub >> 2);
  const int cstage = (sub & 3) * 8;
  const unsigned short* Agp = A + (size_t)(bm * 256 + rstage) * K + cstage;
  const unsigned short* Bgp = Bt + (size_t)(bn * 256 + rstage) * K + cstage;
  const size_t halfoff = (size_t)128 * K;

  const int loff = ((lc >> 1) << 7) + (((((lc & 1) << 2) | lr) ^ (lc >> 1)) << 4);

  f32x4 acc[8][4];
  const f32x4 zero = {0.f, 0.f, 0.f, 0.f};
#pragma unroll
  for (int m = 0; m < 8; ++m)
#pragma unroll
    for (int n = 0; n < 4; ++n) acc[m][n] = zero;

  auto stage = [&](int buf, int t) {
    gload16(Agp + t * 32, &sA[buf][wave * 512]);
    gload16(Agp + halfoff + t * 32, &sA[buf][4096 + wave * 512]);
    gload16(Bgp + t * 32, &sB[buf][wave * 512]);
    gload16(Bgp + halfoff + t * 32, &sB[buf][4096 + wave * 512]);
  };

  const int NT = K >> 5;   // 80
#pragma unroll
  for (int t = 0; t < 3; ++t) stage(t, t);

  const int nj = NT >> 2;
  for (int j = 0; j < nj; ++j) {
#pragma unroll
    for (int to = 0; to < 4; ++to) {
      const int t = (j << 2) + to;
      if (t < NT - 2)       asm volatile("s_waitcnt vmcnt(8)" ::: "memory");
      else if (t == NT - 2) asm volatile("s_waitcnt vmcnt(4)" ::: "memory");
      else                  asm volatile("s_waitcnt vmcnt(0)" ::: "memory");
      __builtin_amdgcn_s_barrier();
      asm volatile("" ::: "memory");

      const char* bufA = (const char*)&sA[to][0];
      const char* bufB = (const char*)&sB[to][0];
      bf16x8 af[8], bfr[4];
#pragma unroll
      for (int mi = 0; mi < 8; ++mi)
        af[mi] = *(const bf16x8*)(bufA + ((wr * 128 + mi * 16) << 6) + loff);
#pragma unroll
      for (int ni = 0; ni < 4; ++ni)
        bfr[ni] = *(const bf16x8*)(bufB + ((wc * 64 + ni * 16) << 6) + loff);

      if (t + 3 < NT) stage((to + 3) & 3, t + 3);

      asm volatile("s_waitcnt lgkmcnt(0)" ::: "memory");
      __builtin_amdgcn_sched_barrier(0);
      __builtin_amdgcn_s_setprio(1);
#pragma unroll
      for (int mi = 0; mi < 8; ++mi)
#pragma unroll
        for (int ni = 0; ni < 4; ++ni)
          acc[mi][ni] = __builtin_amdgcn_mfma_f32_16x16x32_bf16(af[mi], bfr[ni], acc[mi][ni], 0, 0, 0);
      __builtin_amdgcn_s_setprio(0);
    }
  }

  // ---- epilogue: bias + per-wave LDS relayout -> coalesced stores ----
  __builtin_amdgcn_s_barrier();    // all waves done reading K-loop LDS
  const int rowb = bm * 256 + wr * 128;
  const int colb = bn * 256 + wc * 64;
  unsigned short* myl = (wave < 4) ? &sA[wave][0] : &sB[wave - 4][0];
#pragma unroll
  for (int ni = 0; ni < 4; ++ni) {
    const float bv = bias[colb + ni * 16 + lc];
#pragma unroll
    for (int mf = 0; mf < 8; ++mf)
#pragma unroll
      for (int jj = 0; jj < 4; ++jj)
        myl[(mf * 16 + lr * 4 + jj) * 64 + ni * 16 + lc] = f2bf(acc[mf][ni][jj] + bv);
  }
  asm volatile("" ::: "memory");   // wave-local LDS: no cross-wave barrier needed
#pragma unroll
  for (int i = 0; i < 16; ++i) {
    const int idx2 = i * 64 + lane;
    const int r = idx2 >> 3, c = idx2 & 7;
    *(u16x8*)&Cbf[(size_t)(rowb + r) * N + colb + c * 8] = *(const u16x8*)&myl[r * 64 + c * 8];
  }
}

// ---------------- gemm2 (out-proj): 128x128, 3-deep counted vmcnt + 2D XCD --
__global__ __launch_bounds__(256, 3)
void k_gemm_out(const unsigned short* __restrict__ A,
                const unsigned short* __restrict__ Bt,
                const float* __restrict__ bias,
                float* __restrict__ Cf,
                int M, int N, int K) {
  __shared__ unsigned short sA[3][4096];
  __shared__ unsigned short sB[3][4096];
  const int nbm = M >> 7, nbn = N >> 7;     // 32, 20
  const int CM = nbm >> 2, CN = nbn >> 1;   // 8, 10
  int wg = blockIdx.x;
  const int xcd = wg & 7;
  const int idx = wg >> 3;
  const int bm = (xcd >> 1) * CM + idx / CN;
  const int bn = (xcd & 1) * CN + idx % CN;
  const int tid = threadIdx.x;
  const int lane = tid & 63, wave = tid >> 6;
  const int wr = wave >> 1, wc = wave & 1;
  const int lc = lane & 15, lr = lane >> 4;

  const int sub = (lane & 7) ^ (lane >> 3);
  const int rstage = wave * 16 + ((lane >> 3) << 1) + (sub >> 2);
  const int cstage = (sub & 3) * 8;
  const unsigned short* Agp = A + (size_t)(bm * 128 + rstage) * K + cstage;
  const unsigned short* Bgp = Bt + (size_t)(bn * 128 + rstage) * K + cstage;
  const size_t halfoff = (size_t)64 * K;

  const int loff = ((lc >> 1) << 7) + (((((lc & 1) << 2) | lr) ^ (lc >> 1)) << 4);

  f32x4 acc[4][4];
  const f32x4 zero = {0.f, 0.f, 0.f, 0.f};
#pragma unroll
  for (int m = 0; m < 4; ++m)
#pragma unroll
    for (int n = 0; n < 4; ++n) acc[m][n] = zero;

  auto stage = [&](int buf, int t) {
    gload16(Agp + t * 32, &sA[buf][wave * 512]);
    gload16(Agp + halfoff + t * 32, &sA[buf][2048 + wave * 512]);
    gload16(Bgp + t * 32, &sB[buf][wave * 512]);
    gload16(Bgp + halfoff + t * 32, &sB[buf][2048 + wave * 512]);
  };

  const int NT = K >> 5;   // 80
  stage(0, 0);
  stage(1, 1);
  int b0 = 0;
  for (int t = 0; t < NT; ++t) {
    if (t < NT - 1) asm volatile("s_waitcnt vmcnt(4)" ::: "memory");
    else            asm volatile("s_waitcnt vmcnt(0)" ::: "memory");
    __builtin_amdgcn_s_barrier();
    asm volatile("" ::: "memory");

    const char* bufA = (const char*)&sA[b0][0];
    const char* bufB = (const char*)&sB[b0][0];
    bf16x8 af[4], bfr[4];
#pragma unroll
    for (int mi = 0; mi < 4; ++mi)
      af[mi] = *(const bf16x8*)(bufA + ((wr * 64 + mi * 16) << 6) + loff);
#pragma unroll
    for (int ni = 0; ni < 4; ++ni)
      bfr[ni] = *(const bf16x8*)(bufB + ((wc * 64 + ni * 16) << 6) + loff);

    if (t + 2 < NT) {
      int bs = b0 - 1; if (bs < 0) bs = 2;   // (t+2)%3
      stage(bs, t + 2);
    }

    asm volatile("s_waitcnt lgkmcnt(0)" ::: "memory");
    __builtin_amdgcn_sched_barrier(0);
    __builtin_amdgcn_s_setprio(1);
#pragma unroll
    for (int mi = 0; mi < 4; ++mi)
#pragma unroll
      for (int ni = 0; ni < 4; ++ni)
        acc[mi][ni] = __builtin_amdgcn_mfma_f32_16x16x32_bf16(af[mi], bfr[ni], acc[mi][ni], 0, 0, 0);
    __builtin_amdgcn_s_setprio(0);
    ++b0; if (b0 == 3) b0 = 0;
  }

  const int rowb = bm * 128 + wr * 64;
  const int colb = bn * 128 + wc * 64;
#pragma unroll
  for (int ni = 0; ni < 4; ++ni) {
    const int col = colb + ni * 16 + lc;
    const float bv = bias[col];
#pragma unroll
    for (int mf = 0; mf < 4; ++mf) {
#pragma unroll
      for (int jj = 0; jj < 4; ++jj) {
        const int row = rowb + mf * 16 + lr * 4 + jj;
        Cf[(size_t)row * N + col] = acc[mf][ni][jj] + bv;
      }
    }
  }
}

// ---------------- RoPE + head split: qkv -> Q (scaled), K, V^T --------------
__global__ __launch_bounds__(256) void k_rope(const unsigned short* __restrict__ qkv,
                                              unsigned short* __restrict__ Qw,
                                              unsigned short* __restrict__ Kw,
                                              unsigned short* __restrict__ Vt) {
  const int blk = blockIdx.x;
  const int sc = blk & 31;
  const int bh = blk >> 5;
  const int b = bh >> 5, h = bh & 31;
  const int s0 = sc * 64;
  __shared__ float cs0[64][16], sn0[64][16];
  __shared__ unsigned short vbuf[64][88];
  const int tid = threadIdx.x;
  for (int i = tid; i < 64 * 16; i += 256) {
    int sl = i >> 4, fi = i & 15;
    float ang = (float)(s0 + sl) * __expf(-(float)fi * 0.575646273248511421f);
    cs0[sl][fi] = cosf(ang);
    sn0[sl][fi] = sinf(ang);
  }
  const size_t row0 = (size_t)(b * S_LEN + s0) * QKV_N;
  for (int i = tid; i < 64 * 10; i += 256) {
    int sl = i / 10, o = i - sl * 10;
    *(u16x8*)&vbuf[sl][o * 8] =
        *(const u16x8*)&qkv[row0 + (size_t)sl * QKV_N + 2 * HIDDEN + h * HD + o * 8];
  }
  __syncthreads();
  const size_t obase = ((size_t)bh * S_LEN + s0) * DPAD;
  const float SCALE = 0.111803398874989485f;  // 80^-0.5
  for (int i = tid; i < 64 * 12; i += 256) {
    int sl = i / 12, o = i - sl * 12;
    u16x8 outq = {0, 0, 0, 0, 0, 0, 0, 0};
    u16x8 outk = {0, 0, 0, 0, 0, 0, 0, 0};
    if (o < 10) {
      const unsigned short* rp = qkv + row0 + (size_t)sl * QKV_N + h * HD;
      u16x8 xq = *(const u16x8*)(rp + o * 8);
      u16x8 xk = *(const u16x8*)(rp + HIDDEN + o * 8);
      if (o < 2) {
        u16x8 yq = *(const u16x8*)(rp + (o + 2) * 8);
        u16x8 yk = *(const u16x8*)(rp + HIDDEN + (o + 2) * 8);
#pragma unroll
        for (int j = 0; j < 8; ++j) {
          float c = cs0[sl][o * 8 + j], s = sn0[sl][o * 8 + j];
          outq[j] = f2bf((bf2f(xq[j]) * c - bf2f(yq[j]) * s) * SCALE);
          outk[j] = f2bf(bf2f(xk[j]) * c - bf2f(yk[j]) * s);
        }
      } else if (o < 4) {
        u16x8 yq = *(const u16x8*)(rp + (o - 2) * 8);
        u16x8 yk = *(const u16x8*)(rp + HIDDEN + (o - 2) * 8);
#pragma unroll
        for (int j = 0; j < 8; ++j) {
          float c = cs0[sl][(o - 2) * 8 + j], s = sn0[sl][(o - 2) * 8 + j];
          outq[j] = f2bf((bf2f(xq[j]) * c + bf2f(yq[j]) * s) * SCALE);
          outk[j] = f2bf(bf2f(xk[j]) * c + bf2f(yk[j]) * s);
        }
      } else {
#pragma unroll
        for (int j = 0; j < 8; ++j) {
          outq[j] = f2bf(bf2f(xq[j]) * SCALE);
          outk[j] = xk[j];
        }
      }
    }
    *(u16x8*)&Qw[obase + (size_t)sl * DPAD + o * 8] = outq;
    *(u16x8*)&Kw[obase + (size_t)sl * DPAD + o * 8] = outk;
  }
  const size_t vtb = (size_t)bh * DPAD * S_LEN + s0;
  for (int i = tid; i < 80 * 8; i += 256) {
    int d = i >> 3, so = i & 7;
    u16x8 v;
#pragma unroll
    for (int j = 0; j < 8; ++j) v[j] = vbuf[so * 8 + j][d];
    *(u16x8*)&Vt[vtb + (size_t)d * S_LEN + so * 8] = v;
  }
}

// ---------------- flash attention (causal), QBLK=128, KVBLK=64 --------------
// 1-D grid 512: i = p*64 + bh so i%8 == bh%8 -> all 8 p-blocks of a head land
// on ONE XCD (per-XCD K/V working set ~6MB, mostly L2-resident) and each XCD
// gets exactly 64 blocks (2/CU).  Defer-max (T13, THR=8): skip O-rescale when
// no q-row's max grew past m+8.
__global__ __launch_bounds__(256, 2) void k_attn(const unsigned short* __restrict__ Qw,
                                                 const unsigned short* __restrict__ Kw,
                                                 const unsigned short* __restrict__ Vt,
                                                 unsigned short* __restrict__ O) {
  __shared__ unsigned short sK[2][64 * 104];
  __shared__ unsigned short sV[2][80 * 72];
  __shared__ unsigned short sP[4][16 * 72];
  const int p = blockIdx.x >> 6;
  const int bh = blockIdx.x & 63;
  const int b = bh >> 5, h = bh & 31;
  const int tid = threadIdx.x;
  const int wave = tid >> 6, lane = tid & 63;
  const int lr = lane >> 4, lc = lane & 15;
  unsigned short* Pw = &sP[wave][0];

  const unsigned short* Kh = Kw + (size_t)bh * S_LEN * DPAD;
  const unsigned short* Vh = Vt + (size_t)bh * DPAD * S_LEN;
  const unsigned short* Qh = Qw + (size_t)bh * S_LEN * DPAD;

  const int kr = tid >> 2, kc = (tid & 3) * 24;
  const int vr = tid >> 3, vc = (tid & 7) * 8;

  u16x8 kst0, kst1, kst2, vst0, vst1, vst2;
  auto gload = [&](int t) {
    const unsigned short* Kg = Kh + ((size_t)(t * 64 + kr)) * DPAD + kc;
    kst0 = *(const u16x8*)(Kg);
    kst1 = *(const u16x8*)(Kg + 8);
    kst2 = *(const u16x8*)(Kg + 16);
    const unsigned short* Vg = Vh + (size_t)vr * S_LEN + t * 64 + vc;
    vst0 = *(const u16x8*)(Vg);
    vst1 = *(const u16x8*)(Vg + 32 * S_LEN);
    if (tid < 128) vst2 = *(const u16x8*)(Vg + (size_t)64 * S_LEN);
  };
  auto swrite = [&](int buf) {
    *(u16x8*)&sK[buf][kr * 104 + kc] = kst0;
    *(u16x8*)&sK[buf][kr * 104 + kc + 8] = kst1;
    *(u16x8*)&sK[buf][kr * 104 + kc + 16] = kst2;
    *(u16x8*)&sV[buf][vr * 72 + vc] = vst0;
    *(u16x8*)&sV[buf][(vr + 32) * 72 + vc] = vst1;
    if (tid < 128) *(u16x8*)&sV[buf][(vr + 64) * 72 + vc] = vst2;
  };

  const f32x4 zero = {0.f, 0.f, 0.f, 0.f};

#pragma unroll 1
  for (int qi = 0; qi < 2; ++qi) {
    const int qt = qi ? (15 - p) : p;
    const int nt = 2 * qt + 2;
    const int wbase = qt * 128 + wave * 32;

    bf16x8 qf[2][3];
#pragma unroll
    for (int m = 0; m < 2; ++m)
#pragma unroll
      for (int ks = 0; ks < 3; ++ks)
        qf[m][ks] = *(const bf16x8*)&Qh[(size_t)(wbase + m * 16 + lc) * DPAD + ks * 32 + lr * 8];

    f32x4 oacc[2][5];
#pragma unroll
    for (int m = 0; m < 2; ++m)
#pragma unroll
      for (int n = 0; n < 5; ++n) oacc[m][n] = zero;
    float mrun[2] = {-1e30f, -1e30f}, lrun[2] = {0.f, 0.f};

    gload(0);
    __syncthreads();
    swrite(0);
    int cur = 0;

#pragma unroll 1
    for (int t = 0; t < nt; ++t) {
      __syncthreads();
      if (t + 1 < nt) gload(t + 1);
      const int ktb = t * 64;
      const bool act0 = ktb <= wbase + 15;
      const bool act1 = ktb <= wbase + 31;
      if (act1) {
        const unsigned short* Kc = sK[cur];
        const unsigned short* Vc = sV[cur];
        f32x4 sf[2][4];
#pragma unroll
        for (int n = 0; n < 4; ++n) {
          sf[0][n] = zero; sf[1][n] = zero;
#pragma unroll
          for (int ks = 0; ks < 3; ++ks) {
            bf16x8 kf = *(const bf16x8*)&Kc[(n * 16 + lc) * 104 + ks * 32 + lr * 8];
            if (act0) sf[0][n] = __builtin_amdgcn_mfma_f32_16x16x32_bf16(kf, qf[0][ks], sf[0][n], 0, 0, 0);
            sf[1][n] = __builtin_amdgcn_mfma_f32_16x16x32_bf16(kf, qf[1][ks], sf[1][n], 0, 0, 0);
          }
        }
        bf16x8 vf[5][2];
#pragma unroll
        for (int n = 0; n < 5; ++n)
#pragma unroll
          for (int ks = 0; ks < 2; ++ks)
            vf[n][ks] = *(const bf16x8*)&Vc[(n * 16 + lc) * 72 + ks * 32 + lr * 8];
#pragma unroll
        for (int m = 0; m < 2; ++m) {
          if (m == 0 && !act0) continue;
          const int qrow0 = wbase + m * 16;
          if (ktb + 63 > qrow0) {
#pragma unroll
            for (int n = 0; n < 4; ++n)
#pragma unroll
              for (int j = 0; j < 4; ++j)
                if (ktb + n * 16 + lr * 4 + j > qrow0 + lc) sf[m][n][j] = -1e30f;
          }
          float t0 = sf[m][0][0];
#pragma unroll
          for (int n = 0; n < 4; ++n)
#pragma unroll
            for (int j = 0; j < 4; ++j) t0 = fmaxf(t0, sf[m][n][j]);
          t0 = fmaxf(t0, __shfl_xor(t0, 16));
          t0 = fmaxf(t0, __shfl_xor(t0, 32));
          // defer-max: only rescale when some q-row's max grew past m + 8
          const bool need = __any(t0 > mrun[m] + 8.f);
          const float nm = need ? fmaxf(mrun[m], t0) : mrun[m];
          float ps = 0.f;
#pragma unroll
          for (int n = 0; n < 4; ++n)
#pragma unroll
            for (int j = 0; j < 4; ++j) {
              float e = __expf(sf[m][n][j] - nm);
              sf[m][n][j] = e;
              ps += e;
            }
          ps += __shfl_xor(ps, 16);
          ps += __shfl_xor(ps, 32);
          if (need) {
            const float corrq = __expf(mrun[m] - nm);
            mrun[m] = nm;
            lrun[m] = lrun[m] * corrq + ps;
            float cj[4];
#pragma unroll
            for (int j = 0; j < 4; ++j) cj[j] = __shfl(corrq, lr * 4 + j, 16);
#pragma unroll
            for (int n = 0; n < 5; ++n)
#pragma unroll
              for (int j = 0; j < 4; ++j) oacc[m][n][j] *= cj[j];
          } else {
            lrun[m] += ps;
          }
#pragma unroll
          for (int n = 0; n < 4; ++n) {
            unsigned lo = (unsigned)f2bf(sf[m][n][0]) | ((unsigned)f2bf(sf[m][n][1]) << 16);
            unsigned hi = (unsigned)f2bf(sf[m][n][2]) | ((unsigned)f2bf(sf[m][n][3]) << 16);
            uint2 u; u.x = lo; u.y = hi;
            *(uint2*)&Pw[lc * 72 + n * 16 + lr * 4] = u;
          }
          asm volatile("" ::: "memory");
          bf16x8 pa0 = *(const bf16x8*)&Pw[lc * 72 + lr * 8];
          bf16x8 pa1 = *(const bf16x8*)&Pw[lc * 72 + 32 + lr * 8];
#pragma unroll
          for (int n = 0; n < 5; ++n) {
            oacc[m][n] = __builtin_amdgcn_mfma_f32_16x16x32_bf16(pa0, vf[n][0], oacc[m][n], 0, 0, 0);
            oacc[m][n] = __builtin_amdgcn_mfma_f32_16x16x32_bf16(pa1, vf[n][1], oacc[m][n], 0, 0, 0);
          }
          asm volatile("" ::: "memory");
        }
      }
      if (t + 1 < nt) swrite(cur ^ 1);
      cur ^= 1;
    }

#pragma unroll
    for (int m = 0; m < 2; ++m) {
      float linv[4];
#pragma unroll
      for (int j = 0; j < 4; ++j) {
        float lj = __shfl(lrun[m], lr * 4 + j, 16);
        linv[j] = 1.f / lj;
      }
      const int q0 = wbase + m * 16 + lr * 4;
#pragma unroll
      for (int n = 0; n < 5; ++n) {
        const int d = n * 16 + lc;
#pragma unroll
        for (int j = 0; j < 4; ++j)
          O[((size_t)(b * S_LEN) + q0 + j) * HIDDEN + h * HD + d] = f2bf(oacc[m][n][j] * linv[j]);
      }
    }
  }
}

extern "C" void kernel_launch(void* const* d_in, const int* in_sizes, int n_in,
                              void* d_out, int out_size, void* d_ws, size_t ws_size,
                              hipStream_t stream) {
  (void)in_sizes; (void)n_in; (void)out_size; (void)ws_size;
  const float* hidden  = (const float*)d_in[1];
  const float* w_qkv   = (const float*)d_in[2];
  const float* b_qkv   = (const float*)d_in[3];
  const float* w_dense = (const float*)d_in[4];
  const float* b_dense = (const float*)d_in[5];
  char* ws = (char*)d_ws;
  unsigned short* Abf   = (unsigned short*)(ws + 0);          // 4096x2560 bf16
  unsigned short* Wqkvt = (unsigned short*)(ws + 20971520);   // 7680x2560 bf16
  unsigned short* Wdt   = (unsigned short*)(ws + 60293120);   // 2560x2560 bf16
  unsigned short* QKVb  = (unsigned short*)(ws + 73400320);   // 4096x7680 bf16
  unsigned short* Qw    = (unsigned short*)(ws + 136314880);  // 64x2048x96 bf16
  unsigned short* Kw    = (unsigned short*)(ws + 161480704);
  unsigned short* Vt    = (unsigned short*)(ws + 186646528);
  unsigned short* Obf   = (unsigned short*)(ws + 211812352);  // 4096x2560 bf16

  k_cvt<<<10240, 256, 0, stream>>>(hidden, Abf, 2621440);
  k_transpose_bf16<<<dim3(120, 40), 256, 0, stream>>>(w_qkv, Wqkvt, 2560, 7680);
  k_transpose_bf16<<<dim3(40, 40), 256, 0, stream>>>(w_dense, Wdt, 2560, 2560);
  k_gemm_qkv<<<480, 512, 0, stream>>>(Abf, Wqkvt, b_qkv, QKVb, 4096, 7680, 2560);
  k_rope<<<2048, 256, 0, stream>>>(QKVb, Qw, Kw, Vt);
  k_attn<<<512, 256, 0, stream>>>(Qw, Kw, Vt, Obf);
  k_gemm_out<<<640, 256, 0, stream>>>(Obf, Wdt, b_dense, (float*)d_out, 4096, 2560, 2560);
}

// Round 16
// 400.036 us; speedup vs baseline: 4.8393x; 1.0080x over previous
//
#include <hip/hip_runtime.h>

#define S_LEN 2048
#define NHEAD 32
#define HD 80
#define DPAD 96
#define HIDDEN 2560
#define QKV_N 7680

typedef __attribute__((ext_vector_type(8))) short bf16x8;
typedef __attribute__((ext_vector_type(8))) unsigned short u16x8;
typedef __attribute__((ext_vector_type(4))) float f32x4;

__device__ __forceinline__ unsigned short f2bf(float f) {
  unsigned int u = __float_as_uint(f);
  u += 0x7fffu + ((u >> 16) & 1u);   // RNE
  return (unsigned short)(u >> 16);
}
__device__ __forceinline__ float bf2f(unsigned short h) {
  return __uint_as_float(((unsigned int)h) << 16);
}

__device__ __forceinline__ void gload16(const void* g, void* l) {
  __builtin_amdgcn_global_load_lds((const __attribute__((address_space(1))) void*)g,
                                   (__attribute__((address_space(3))) void*)l, 16, 0, 0);
}

// ---------------- fused prep: fp32->bf16 cvt + both weight transposes -------
// blocks [0,10240): cvt hidden (2621440 float4s)
// blocks [10240,15040): transpose w_qkv (120 x 40 tiles)
// blocks [15040,16640): transpose w_dense (40 x 40 tiles)
__global__ __launch_bounds__(256) void k_prep(const float* __restrict__ hidden,
                                              unsigned short* __restrict__ Abf,
                                              const float* __restrict__ w_qkv,
                                              unsigned short* __restrict__ Wqkvt,
                                              const float* __restrict__ w_dense,
                                              unsigned short* __restrict__ Wdt) {
  __shared__ float tile[64][68];
  const int blk = blockIdx.x;
  if (blk < 10240) {
    int i = blk * 256 + threadIdx.x;
    float4 v = reinterpret_cast<const float4*>(hidden)[i];
    ushort4 o;
    o.x = f2bf(v.x); o.y = f2bf(v.y); o.z = f2bf(v.z); o.w = f2bf(v.w);
    reinterpret_cast<ushort4*>(Abf)[i] = o;
    return;
  }
  const float* in;
  unsigned short* out;
  int R, C, tc, tr;
  if (blk < 15040) {
    int t = blk - 10240;
    in = w_qkv; out = Wqkvt; R = 2560; C = 7680;
    tc = (t % 120) * 64; tr = (t / 120) * 64;
  } else {
    int t = blk - 15040;
    in = w_dense; out = Wdt; R = 2560; C = 2560;
    tc = (t % 40) * 64; tr = (t / 40) * 64;
  }
  for (int i = threadIdx.x; i < 64 * 16; i += 256) {
    int r = i >> 4, c4 = i & 15;
    float4 v = *(const float4*)&in[(size_t)(tr + r) * C + tc + c4 * 4];
    *(float4*)&tile[r][c4 * 4] = v;
  }
  __syncthreads();
  for (int i = threadIdx.x; i < 8 * 64; i += 256) {
    int ro = i >> 6, c = i & 63;
    u16x8 v;
#pragma unroll
    for (int j = 0; j < 8; ++j) v[j] = f2bf(tile[ro * 8 + j][c]);
    *(u16x8*)&out[(size_t)(tc + c) * R + tr + ro * 8] = v;
  }
}

// ---------------- gemm1 (QKV): 256x256, BK=32, R15-exact ---------------------
__global__ __launch_bounds__(512, 2)
void k_gemm_qkv(const unsigned short* __restrict__ A,
                const unsigned short* __restrict__ Bt,
                const float* __restrict__ bias,
                unsigned short* __restrict__ Cbf,
                int M, int N, int K) {
  __shared__ unsigned short sA[4][8192];
  __shared__ unsigned short sB[4][8192];
  const int nbm = M >> 8, nbn = N >> 8;
  const int CM = nbm >> 2, CN = nbn >> 1;   // 2D XCD chunks (4bm x 15bn)
  int wg = blockIdx.x;
  const int xcd = wg & 7;
  const int idx = wg >> 3;
  const int bm = (xcd >> 1) * CM + idx / CN;
  const int bn = (xcd & 1) * CN + idx % CN;
  const int tid = threadIdx.x;
  const int lane = tid & 63, wave = tid >> 6;
  const int wr = wave >> 2, wc = wave & 3;
  const int lc = lane & 15, lr = lane >> 4;

  const int sub = (lane & 7) ^ (lane >> 3);
  const int rstage = wave * 16 + ((lane >> 3) << 1) + (sub >> 2);
  const int cstage = (sub & 3) * 8;
  const unsigned short* Agp = A + (size_t)(bm * 256 + rstage) * K + cstage;
  const unsigned short* Bgp = Bt + (size_t)(bn * 256 + rstage) * K + cstage;
  const size_t halfoff = (size_t)128 * K;

  const int loff = ((lc >> 1) << 7) + (((((lc & 1) << 2) | lr) ^ (lc >> 1)) << 4);

  f32x4 acc[8][4];
  const f32x4 zero = {0.f, 0.f, 0.f, 0.f};
#pragma unroll
  for (int m = 0; m < 8; ++m)
#pragma unroll
    for (int n = 0; n < 4; ++n) acc[m][n] = zero;

  auto stage = [&](int buf, int t) {
    gload16(Agp + t * 32, &sA[buf][wave * 512]);
    gload16(Agp + halfoff + t * 32, &sA[buf][4096 + wave * 512]);
    gload16(Bgp + t * 32, &sB[buf][wave * 512]);
    gload16(Bgp + halfoff + t * 32, &sB[buf][4096 + wave * 512]);
  };

  const int NT = K >> 5;   // 80
#pragma unroll
  for (int t = 0; t < 3; ++t) stage(t, t);

  const int nj = NT >> 2;
  for (int j = 0; j < nj; ++j) {
#pragma unroll
    for (int to = 0; to < 4; ++to) {
      const int t = (j << 2) + to;
      if (t < NT - 2)       asm volatile("s_waitcnt vmcnt(8)" ::: "memory");
      else if (t == NT - 2) asm volatile("s_waitcnt vmcnt(4)" ::: "memory");
      else                  asm volatile("s_waitcnt vmcnt(0)" ::: "memory");
      __builtin_amdgcn_s_barrier();
      asm volatile("" ::: "memory");

      const char* bufA = (const char*)&sA[to][0];
      const char* bufB = (const char*)&sB[to][0];
      bf16x8 af[8], bfr[4];
#pragma unroll
      for (int mi = 0; mi < 8; ++mi)
        af[mi] = *(const bf16x8*)(bufA + ((wr * 128 + mi * 16) << 6) + loff);
#pragma unroll
      for (int ni = 0; ni < 4; ++ni)
        bfr[ni] = *(const bf16x8*)(bufB + ((wc * 64 + ni * 16) << 6) + loff);

      if (t + 3 < NT) stage((to + 3) & 3, t + 3);

      asm volatile("s_waitcnt lgkmcnt(0)" ::: "memory");
      __builtin_amdgcn_sched_barrier(0);
      __builtin_amdgcn_s_setprio(1);
#pragma unroll
      for (int mi = 0; mi < 8; ++mi)
#pragma unroll
        for (int ni = 0; ni < 4; ++ni)
          acc[mi][ni] = __builtin_amdgcn_mfma_f32_16x16x32_bf16(af[mi], bfr[ni], acc[mi][ni], 0, 0, 0);
      __builtin_amdgcn_s_setprio(0);
    }
  }

  // epilogue: bias + per-wave LDS relayout -> coalesced u16x8 stores
  __builtin_amdgcn_s_barrier();
  const int rowb = bm * 256 + wr * 128;
  const int colb = bn * 256 + wc * 64;
  unsigned short* myl = (wave < 4) ? &sA[wave][0] : &sB[wave - 4][0];
#pragma unroll
  for (int ni = 0; ni < 4; ++ni) {
    const float bv = bias[colb + ni * 16 + lc];
#pragma unroll
    for (int mf = 0; mf < 8; ++mf)
#pragma unroll
      for (int jj = 0; jj < 4; ++jj)
        myl[(mf * 16 + lr * 4 + jj) * 64 + ni * 16 + lc] = f2bf(acc[mf][ni][jj] + bv);
  }
  asm volatile("" ::: "memory");
#pragma unroll
  for (int i = 0; i < 16; ++i) {
    const int idx2 = i * 64 + lane;
    const int r = idx2 >> 3, c = idx2 & 7;
    *(u16x8*)&Cbf[(size_t)(rowb + r) * N + colb + c * 8] = *(const u16x8*)&myl[r * 64 + c * 8];
  }
}

// ---------------- gemm2 (out-proj): 128x128, 3-deep + coalesced f32 epilogue -
__global__ __launch_bounds__(256, 3)
void k_gemm_out(const unsigned short* __restrict__ A,
                const unsigned short* __restrict__ Bt,
                const float* __restrict__ bias,
                float* __restrict__ Cf,
                int M, int N, int K) {
  __shared__ unsigned short smem[24576];   // 48 KB: sA = [0,12288), sB = [12288,24576)
  const int nbm = M >> 7, nbn = N >> 7;     // 32, 20
  const int CM = nbm >> 2, CN = nbn >> 1;   // 8, 10
  int wg = blockIdx.x;
  const int xcd = wg & 7;
  const int idx = wg >> 3;
  const int bm = (xcd >> 1) * CM + idx / CN;
  const int bn = (xcd & 1) * CN + idx % CN;
  const int tid = threadIdx.x;
  const int lane = tid & 63, wave = tid >> 6;
  const int wr = wave >> 1, wc = wave & 1;
  const int lc = lane & 15, lr = lane >> 4;

  const int sub = (lane & 7) ^ (lane >> 3);
  const int rstage = wave * 16 + ((lane >> 3) << 1) + (sub >> 2);
  const int cstage = (sub & 3) * 8;
  const unsigned short* Agp = A + (size_t)(bm * 128 + rstage) * K + cstage;
  const unsigned short* Bgp = Bt + (size_t)(bn * 128 + rstage) * K + cstage;
  const size_t halfoff = (size_t)64 * K;

  const int loff = ((lc >> 1) << 7) + (((((lc & 1) << 2) | lr) ^ (lc >> 1)) << 4);

  f32x4 acc[4][4];
  const f32x4 zero = {0.f, 0.f, 0.f, 0.f};
#pragma unroll
  for (int m = 0; m < 4; ++m)
#pragma unroll
    for (int n = 0; n < 4; ++n) acc[m][n] = zero;

  auto stage = [&](int buf, int t) {
    unsigned short* sa = &smem[buf * 4096];
    unsigned short* sb = &smem[12288 + buf * 4096];
    gload16(Agp + t * 32, sa + wave * 512);
    gload16(Agp + halfoff + t * 32, sa + 2048 + wave * 512);
    gload16(Bgp + t * 32, sb + wave * 512);
    gload16(Bgp + halfoff + t * 32, sb + 2048 + wave * 512);
  };

  const int NT = K >> 5;   // 80
  stage(0, 0);
  stage(1, 1);
  int b0 = 0;
  for (int t = 0; t < NT; ++t) {
    if (t < NT - 1) asm volatile("s_waitcnt vmcnt(4)" ::: "memory");
    else            asm volatile("s_waitcnt vmcnt(0)" ::: "memory");
    __builtin_amdgcn_s_barrier();
    asm volatile("" ::: "memory");

    const char* bufA = (const char*)&smem[b0 * 4096];
    const char* bufB = (const char*)&smem[12288 + b0 * 4096];
    bf16x8 af[4], bfr[4];
#pragma unroll
    for (int mi = 0; mi < 4; ++mi)
      af[mi] = *(const bf16x8*)(bufA + ((wr * 64 + mi * 16) << 6) + loff);
#pragma unroll
    for (int ni = 0; ni < 4; ++ni)
      bfr[ni] = *(const bf16x8*)(bufB + ((wc * 64 + ni * 16) << 6) + loff);

    if (t + 2 < NT) {
      int bs = b0 - 1; if (bs < 0) bs = 2;   // (t+2)%3
      stage(bs, t + 2);
    }

    asm volatile("s_waitcnt lgkmcnt(0)" ::: "memory");
    __builtin_amdgcn_sched_barrier(0);
    __builtin_amdgcn_s_setprio(1);
#pragma unroll
    for (int mi = 0; mi < 4; ++mi)
#pragma unroll
      for (int ni = 0; ni < 4; ++ni)
        acc[mi][ni] = __builtin_amdgcn_mfma_f32_16x16x32_bf16(af[mi], bfr[ni], acc[mi][ni], 0, 0, 0);
    __builtin_amdgcn_s_setprio(0);
    ++b0; if (b0 == 3) b0 = 0;
  }

  // epilogue: 2-pass per-wave LDS relayout -> coalesced float4 stores
  __builtin_amdgcn_s_barrier();
  const int rowb = bm * 128 + wr * 64;
  const int colb = bn * 128 + wc * 64;
  float* fw = (float*)smem + wave * 2112;   // 32 rows x 66 floats per wave
#pragma unroll
  for (int p2 = 0; p2 < 2; ++p2) {
#pragma unroll
    for (int mfi = 0; mfi < 2; ++mfi) {
      const int mf = p2 * 2 + mfi;
#pragma unroll
      for (int ni = 0; ni < 4; ++ni) {
        const float bv = bias[colb + ni * 16 + lc];
#pragma unroll
        for (int jj = 0; jj < 4; ++jj)
          fw[(mfi * 16 + lr * 4 + jj) * 66 + ni * 16 + lc] = acc[mf][ni][jj] + bv;
      }
    }
    asm volatile("" ::: "memory");
#pragma unroll
    for (int i = 0; i < 8; ++i) {
      const int idx2 = i * 64 + lane;
      const int r = idx2 >> 4, c4 = idx2 & 15;
      *(float4*)&Cf[(size_t)(rowb + p2 * 32 + r) * N + colb + c4 * 4] =
          *(const float4*)&fw[r * 66 + c4 * 4];
    }
    asm volatile("" ::: "memory");
  }
}

// ---------------- RoPE + head split: qkv -> Q (scaled), K, V^T --------------
__global__ __launch_bounds__(256) void k_rope(const unsigned short* __restrict__ qkv,
                                              unsigned short* __restrict__ Qw,
                                              unsigned short* __restrict__ Kw,
                                              unsigned short* __restrict__ Vt) {
  const int blk = blockIdx.x;
  const int sc = blk & 31;
  const int bh = blk >> 5;
  const int b = bh >> 5, h = bh & 31;
  const int s0 = sc * 64;
  __shared__ float cs0[64][16], sn0[64][16];
  __shared__ unsigned short vbuf[64][88];
  const int tid = threadIdx.x;
  for (int i = tid; i < 64 * 16; i += 256) {
    int sl = i >> 4, fi = i & 15;
    float ang = (float)(s0 + sl) * __expf(-(float)fi * 0.575646273248511421f);
    cs0[sl][fi] = cosf(ang);
    sn0[sl][fi] = sinf(ang);
  }
  const size_t row0 = (size_t)(b * S_LEN + s0) * QKV_N;
  for (int i = tid; i < 64 * 10; i += 256) {
    int sl = i / 10, o = i - sl * 10;
    *(u16x8*)&vbuf[sl][o * 8] =
        *(const u16x8*)&qkv[row0 + (size_t)sl * QKV_N + 2 * HIDDEN + h * HD + o * 8];
  }
  __syncthreads();
  const size_t obase = ((size_t)bh * S_LEN + s0) * DPAD;
  const float SCALE = 0.111803398874989485f;  // 80^-0.5
  for (int i = tid; i < 64 * 12; i += 256) {
    int sl = i / 12, o = i - sl * 12;
    u16x8 outq = {0, 0, 0, 0, 0, 0, 0, 0};
    u16x8 outk = {0, 0, 0, 0, 0, 0, 0, 0};
    if (o < 10) {
      const unsigned short* rp = qkv + row0 + (size_t)sl * QKV_N + h * HD;
      u16x8 xq = *(const u16x8*)(rp + o * 8);
      u16x8 xk = *(const u16x8*)(rp + HIDDEN + o * 8);
      if (o < 2) {
        u16x8 yq = *(const u16x8*)(rp + (o + 2) * 8);
        u16x8 yk = *(const u16x8*)(rp + HIDDEN + (o + 2) * 8);
#pragma unroll
        for (int j = 0; j < 8; ++j) {
          float c = cs0[sl][o * 8 + j], s = sn0[sl][o * 8 + j];
          outq[j] = f2bf((bf2f(xq[j]) * c - bf2f(yq[j]) * s) * SCALE);
          outk[j] = f2bf(bf2f(xk[j]) * c - bf2f(yk[j]) * s);
        }
      } else if (o < 4) {
        u16x8 yq = *(const u16x8*)(rp + (o - 2) * 8);
        u16x8 yk = *(const u16x8*)(rp + HIDDEN + (o - 2) * 8);
#pragma unroll
        for (int j = 0; j < 8; ++j) {
          float c = cs0[sl][(o - 2) * 8 + j], s = sn0[sl][(o - 2) * 8 + j];
          outq[j] = f2bf((bf2f(xq[j]) * c + bf2f(yq[j]) * s) * SCALE);
          outk[j] = f2bf(bf2f(xk[j]) * c + bf2f(yk[j]) * s);
        }
      } else {
#pragma unroll
        for (int j = 0; j < 8; ++j) {
          outq[j] = f2bf(bf2f(xq[j]) * SCALE);
          outk[j] = xk[j];
        }
      }
    }
    *(u16x8*)&Qw[obase + (size_t)sl * DPAD + o * 8] = outq;
    *(u16x8*)&Kw[obase + (size_t)sl * DPAD + o * 8] = outk;
  }
  const size_t vtb = (size_t)bh * DPAD * S_LEN + s0;
  for (int i = tid; i < 80 * 8; i += 256) {
    int d = i >> 3, so = i & 7;
    u16x8 v;
#pragma unroll
    for (int j = 0; j < 8; ++j) v[j] = vbuf[so * 8 + j][d];
    *(u16x8*)&Vt[vtb + (size_t)d * S_LEN + so * 8] = v;
  }
}

// ---------------- flash attention (causal), R15-exact ------------------------
__global__ __launch_bounds__(256, 2) void k_attn(const unsigned short* __restrict__ Qw,
                                                 const unsigned short* __restrict__ Kw,
                                                 const unsigned short* __restrict__ Vt,
                                                 unsigned short* __restrict__ O) {
  __shared__ unsigned short sK[2][64 * 104];
  __shared__ unsigned short sV[2][80 * 72];
  __shared__ unsigned short sP[4][16 * 72];
  const int p = blockIdx.x >> 6;
  const int bh = blockIdx.x & 63;
  const int b = bh >> 5, h = bh & 31;
  const int tid = threadIdx.x;
  const int wave = tid >> 6, lane = tid & 63;
  const int lr = lane >> 4, lc = lane & 15;
  unsigned short* Pw = &sP[wave][0];

  const unsigned short* Kh = Kw + (size_t)bh * S_LEN * DPAD;
  const unsigned short* Vh = Vt + (size_t)bh * DPAD * S_LEN;
  const unsigned short* Qh = Qw + (size_t)bh * S_LEN * DPAD;

  const int kr = tid >> 2, kc = (tid & 3) * 24;
  const int vr = tid >> 3, vc = (tid & 7) * 8;

  u16x8 kst0, kst1, kst2, vst0, vst1, vst2;
  auto gload = [&](int t) {
    const unsigned short* Kg = Kh + ((size_t)(t * 64 + kr)) * DPAD + kc;
    kst0 = *(const u16x8*)(Kg);
    kst1 = *(const u16x8*)(Kg + 8);
    kst2 = *(const u16x8*)(Kg + 16);
    const unsigned short* Vg = Vh + (size_t)vr * S_LEN + t * 64 + vc;
    vst0 = *(const u16x8*)(Vg);
    vst1 = *(const u16x8*)(Vg + 32 * S_LEN);
    if (tid < 128) vst2 = *(const u16x8*)(Vg + (size_t)64 * S_LEN);
  };
  auto swrite = [&](int buf) {
    *(u16x8*)&sK[buf][kr * 104 + kc] = kst0;
    *(u16x8*)&sK[buf][kr * 104 + kc + 8] = kst1;
    *(u16x8*)&sK[buf][kr * 104 + kc + 16] = kst2;
    *(u16x8*)&sV[buf][vr * 72 + vc] = vst0;
    *(u16x8*)&sV[buf][(vr + 32) * 72 + vc] = vst1;
    if (tid < 128) *(u16x8*)&sV[buf][(vr + 64) * 72 + vc] = vst2;
  };

  const f32x4 zero = {0.f, 0.f, 0.f, 0.f};

#pragma unroll 1
  for (int qi = 0; qi < 2; ++qi) {
    const int qt = qi ? (15 - p) : p;
    const int nt = 2 * qt + 2;
    const int wbase = qt * 128 + wave * 32;

    bf16x8 qf[2][3];
#pragma unroll
    for (int m = 0; m < 2; ++m)
#pragma unroll
      for (int ks = 0; ks < 3; ++ks)
        qf[m][ks] = *(const bf16x8*)&Qh[(size_t)(wbase + m * 16 + lc) * DPAD + ks * 32 + lr * 8];

    f32x4 oacc[2][5];
#pragma unroll
    for (int m = 0; m < 2; ++m)
#pragma unroll
      for (int n = 0; n < 5; ++n) oacc[m][n] = zero;
    float mrun[2] = {-1e30f, -1e30f}, lrun[2] = {0.f, 0.f};

    gload(0);
    __syncthreads();
    swrite(0);
    int cur = 0;

#pragma unroll 1
    for (int t = 0; t < nt; ++t) {
      __syncthreads();
      if (t + 1 < nt) gload(t + 1);
      const int ktb = t * 64;
      const bool act0 = ktb <= wbase + 15;
      const bool act1 = ktb <= wbase + 31;
      if (act1) {
        const unsigned short* Kc = sK[cur];
        const unsigned short* Vc = sV[cur];
        f32x4 sf[2][4];
#pragma unroll
        for (int n = 0; n < 4; ++n) {
          sf[0][n] = zero; sf[1][n] = zero;
#pragma unroll
          for (int ks = 0; ks < 3; ++ks) {
            bf16x8 kf = *(const bf16x8*)&Kc[(n * 16 + lc) * 104 + ks * 32 + lr * 8];
            if (act0) sf[0][n] = __builtin_amdgcn_mfma_f32_16x16x32_bf16(kf, qf[0][ks], sf[0][n], 0, 0, 0);
            sf[1][n] = __builtin_amdgcn_mfma_f32_16x16x32_bf16(kf, qf[1][ks], sf[1][n], 0, 0, 0);
          }
        }
        bf16x8 vf[5][2];
#pragma unroll
        for (int n = 0; n < 5; ++n)
#pragma unroll
          for (int ks = 0; ks < 2; ++ks)
            vf[n][ks] = *(const bf16x8*)&Vc[(n * 16 + lc) * 72 + ks * 32 + lr * 8];
#pragma unroll
        for (int m = 0; m < 2; ++m) {
          if (m == 0 && !act0) continue;
          const int qrow0 = wbase + m * 16;
          if (ktb + 63 > qrow0) {
#pragma unroll
            for (int n = 0; n < 4; ++n)
#pragma unroll
              for (int j = 0; j < 4; ++j)
                if (ktb + n * 16 + lr * 4 + j > qrow0 + lc) sf[m][n][j] = -1e30f;
          }
          float t0 = sf[m][0][0];
#pragma unroll
          for (int n = 0; n < 4; ++n)
#pragma unroll
            for (int j = 0; j < 4; ++j) t0 = fmaxf(t0, sf[m][n][j]);
          t0 = fmaxf(t0, __shfl_xor(t0, 16));
          t0 = fmaxf(t0, __shfl_xor(t0, 32));
          const bool need = __any(t0 > mrun[m] + 8.f);
          const float nm = need ? fmaxf(mrun[m], t0) : mrun[m];
          float ps = 0.f;
#pragma unroll
          for (int n = 0; n < 4; ++n)
#pragma unroll
            for (int j = 0; j < 4; ++j) {
              float e = __expf(sf[m][n][j] - nm);
              sf[m][n][j] = e;
              ps += e;
            }
          ps += __shfl_xor(ps, 16);
          ps += __shfl_xor(ps, 32);
          if (need) {
            const float corrq = __expf(mrun[m] - nm);
            mrun[m] = nm;
            lrun[m] = lrun[m] * corrq + ps;
            float cj[4];
#pragma unroll
            for (int j = 0; j < 4; ++j) cj[j] = __shfl(corrq, lr * 4 + j, 16);
#pragma unroll
            for (int n = 0; n < 5; ++n)
#pragma unroll
              for (int j = 0; j < 4; ++j) oacc[m][n][j] *= cj[j];
          } else {
            lrun[m] += ps;
          }
#pragma unroll
          for (int n = 0; n < 4; ++n) {
            unsigned lo = (unsigned)f2bf(sf[m][n][0]) | ((unsigned)f2bf(sf[m][n][1]) << 16);
            unsigned hi = (unsigned)f2bf(sf[m][n][2]) | ((unsigned)f2bf(sf[m][n][3]) << 16);
            uint2 u; u.x = lo; u.y = hi;
            *(uint2*)&Pw[lc * 72 + n * 16 + lr * 4] = u;
          }
          asm volatile("" ::: "memory");
          bf16x8 pa0 = *(const bf16x8*)&Pw[lc * 72 + lr * 8];
          bf16x8 pa1 = *(const bf16x8*)&Pw[lc * 72 + 32 + lr * 8];
#pragma unroll
          for (int n = 0; n < 5; ++n) {
            oacc[m][n] = __builtin_amdgcn_mfma_f32_16x16x32_bf16(pa0, vf[n][0], oacc[m][n], 0, 0, 0);
            oacc[m][n] = __builtin_amdgcn_mfma_f32_16x16x32_bf16(pa1, vf[n][1], oacc[m][n], 0, 0, 0);
          }
          asm volatile("" ::: "memory");
        }
      }
      if (t + 1 < nt) swrite(cur ^ 1);
      cur ^= 1;
    }

#pragma unroll
    for (int m = 0; m < 2; ++m) {
      float linv[4];
#pragma unroll
      for (int j = 0; j < 4; ++j) {
        float lj = __shfl(lrun[m], lr * 4 + j, 16);
        linv[j] = 1.f / lj;
      }
      const int q0 = wbase + m * 16 + lr * 4;
#pragma unroll
      for (int n = 0; n < 5; ++n) {
        const int d = n * 16 + lc;
#pragma unroll
        for (int j = 0; j < 4; ++j)
          O[((size_t)(b * S_LEN) + q0 + j) * HIDDEN + h * HD + d] = f2bf(oacc[m][n][j] * linv[j]);
      }
    }
  }
}

extern "C" void kernel_launch(void* const* d_in, const int* in_sizes, int n_in,
                              void* d_out, int out_size, void* d_ws, size_t ws_size,
                              hipStream_t stream) {
  (void)in_sizes; (void)n_in; (void)out_size; (void)ws_size;
  const float* hidden  = (const float*)d_in[1];
  const float* w_qkv   = (const float*)d_in[2];
  const float* b_qkv   = (const float*)d_in[3];
  const float* w_dense = (const float*)d_in[4];
  const float* b_dense = (const float*)d_in[5];
  char* ws = (char*)d_ws;
  unsigned short* Abf   = (unsigned short*)(ws + 0);          // 4096x2560 bf16
  unsigned short* Wqkvt = (unsigned short*)(ws + 20971520);   // 7680x2560 bf16
  unsigned short* Wdt   = (unsigned short*)(ws + 60293120);   // 2560x2560 bf16
  unsigned short* QKVb  = (unsigned short*)(ws + 73400320);   // 4096x7680 bf16
  unsigned short* Qw    = (unsigned short*)(ws + 136314880);  // 64x2048x96 bf16
  unsigned short* Kw    = (unsigned short*)(ws + 161480704);
  unsigned short* Vt    = (unsigned short*)(ws + 186646528);
  unsigned short* Obf   = (unsigned short*)(ws + 211812352);  // 4096x2560 bf16

  k_prep<<<16640, 256, 0, stream>>>(hidden, Abf, w_qkv, Wqkvt, w_dense, Wdt);
  k_gemm_qkv<<<480, 512, 0, stream>>>(Abf, Wqkvt, b_qkv, QKVb, 4096, 7680, 2560);
  k_rope<<<2048, 256, 0, stream>>>(QKVb, Qw, Kw, Vt);
  k_attn<<<512, 256, 0, stream>>>(Qw, Kw, Vt, Obf);
  k_gemm_out<<<640, 256, 0, stream>>>(Obf, Wdt, b_dense, (float*)d_out, 4096, 2560, 2560);
}

// Round 17
// 394.028 us; speedup vs baseline: 4.9131x; 1.0153x over previous
//
#include <hip/hip_runtime.h>

#define S_LEN 2048
#define NHEAD 32
#define HD 80
#define DPAD 96
#define HIDDEN 2560
#define QKV_N 7680

typedef __attribute__((ext_vector_type(8))) short bf16x8;
typedef __attribute__((ext_vector_type(8))) unsigned short u16x8;
typedef __attribute__((ext_vector_type(4))) float f32x4;

__device__ __forceinline__ unsigned short f2bf(float f) {
  unsigned int u = __float_as_uint(f);
  u += 0x7fffu + ((u >> 16) & 1u);   // RNE
  return (unsigned short)(u >> 16);
}
__device__ __forceinline__ float bf2f(unsigned short h) {
  return __uint_as_float(((unsigned int)h) << 16);
}

__device__ __forceinline__ void gload16(const void* g, void* l) {
  __builtin_amdgcn_global_load_lds((const __attribute__((address_space(1))) void*)g,
                                   (__attribute__((address_space(3))) void*)l, 16, 0, 0);
}

// ---------------- fused prep: fp32->bf16 cvt + both weight transposes -------
__global__ __launch_bounds__(256) void k_prep(const float* __restrict__ hidden,
                                              unsigned short* __restrict__ Abf,
                                              const float* __restrict__ w_qkv,
                                              unsigned short* __restrict__ Wqkvt,
                                              const float* __restrict__ w_dense,
                                              unsigned short* __restrict__ Wdt) {
  __shared__ float tile[64][68];
  const int blk = blockIdx.x;
  if (blk < 10240) {
    int i = blk * 256 + threadIdx.x;
    float4 v = reinterpret_cast<const float4*>(hidden)[i];
    ushort4 o;
    o.x = f2bf(v.x); o.y = f2bf(v.y); o.z = f2bf(v.z); o.w = f2bf(v.w);
    reinterpret_cast<ushort4*>(Abf)[i] = o;
    return;
  }
  const float* in;
  unsigned short* out;
  int R, C, tc, tr;
  if (blk < 15040) {
    int t = blk - 10240;
    in = w_qkv; out = Wqkvt; R = 2560; C = 7680;
    tc = (t % 120) * 64; tr = (t / 120) * 64;
  } else {
    int t = blk - 15040;
    in = w_dense; out = Wdt; R = 2560; C = 2560;
    tc = (t % 40) * 64; tr = (t / 40) * 64;
  }
  for (int i = threadIdx.x; i < 64 * 16; i += 256) {
    int r = i >> 4, c4 = i & 15;
    float4 v = *(const float4*)&in[(size_t)(tr + r) * C + tc + c4 * 4];
    *(float4*)&tile[r][c4 * 4] = v;
  }
  __syncthreads();
  for (int i = threadIdx.x; i < 8 * 64; i += 256) {
    int ro = i >> 6, c = i & 63;
    u16x8 v;
#pragma unroll
    for (int j = 0; j < 8; ++j) v[j] = f2bf(tile[ro * 8 + j][c]);
    *(u16x8*)&out[(size_t)(tc + c) * R + tr + ro * 8] = v;
  }
}

// ---------------- gemm1 (QKV): 256x256, BK=32, R15-exact ---------------------
__global__ __launch_bounds__(512, 2)
void k_gemm_qkv(const unsigned short* __restrict__ A,
                const unsigned short* __restrict__ Bt,
                const float* __restrict__ bias,
                unsigned short* __restrict__ Cbf,
                int M, int N, int K) {
  __shared__ unsigned short sA[4][8192];
  __shared__ unsigned short sB[4][8192];
  const int nbm = M >> 8, nbn = N >> 8;
  const int CM = nbm >> 2, CN = nbn >> 1;
  int wg = blockIdx.x;
  const int xcd = wg & 7;
  const int idx = wg >> 3;
  const int bm = (xcd >> 1) * CM + idx / CN;
  const int bn = (xcd & 1) * CN + idx % CN;
  const int tid = threadIdx.x;
  const int lane = tid & 63, wave = tid >> 6;
  const int wr = wave >> 2, wc = wave & 3;
  const int lc = lane & 15, lr = lane >> 4;

  const int sub = (lane & 7) ^ (lane >> 3);
  const int rstage = wave * 16 + ((lane >> 3) << 1) + (sub >> 2);
  const int cstage = (sub & 3) * 8;
  const unsigned short* Agp = A + (size_t)(bm * 256 + rstage) * K + cstage;
  const unsigned short* Bgp = Bt + (size_t)(bn * 256 + rstage) * K + cstage;
  const size_t halfoff = (size_t)128 * K;

  const int loff = ((lc >> 1) << 7) + (((((lc & 1) << 2) | lr) ^ (lc >> 1)) << 4);

  f32x4 acc[8][4];
  const f32x4 zero = {0.f, 0.f, 0.f, 0.f};
#pragma unroll
  for (int m = 0; m < 8; ++m)
#pragma unroll
    for (int n = 0; n < 4; ++n) acc[m][n] = zero;

  auto stage = [&](int buf, int t) {
    gload16(Agp + t * 32, &sA[buf][wave * 512]);
    gload16(Agp + halfoff + t * 32, &sA[buf][4096 + wave * 512]);
    gload16(Bgp + t * 32, &sB[buf][wave * 512]);
    gload16(Bgp + halfoff + t * 32, &sB[buf][4096 + wave * 512]);
  };

  const int NT = K >> 5;   // 80
#pragma unroll
  for (int t = 0; t < 3; ++t) stage(t, t);

  const int nj = NT >> 2;
  for (int j = 0; j < nj; ++j) {
#pragma unroll
    for (int to = 0; to < 4; ++to) {
      const int t = (j << 2) + to;
      if (t < NT - 2)       asm volatile("s_waitcnt vmcnt(8)" ::: "memory");
      else if (t == NT - 2) asm volatile("s_waitcnt vmcnt(4)" ::: "memory");
      else                  asm volatile("s_waitcnt vmcnt(0)" ::: "memory");
      __builtin_amdgcn_s_barrier();
      asm volatile("" ::: "memory");

      const char* bufA = (const char*)&sA[to][0];
      const char* bufB = (const char*)&sB[to][0];
      bf16x8 af[8], bfr[4];
#pragma unroll
      for (int mi = 0; mi < 8; ++mi)
        af[mi] = *(const bf16x8*)(bufA + ((wr * 128 + mi * 16) << 6) + loff);
#pragma unroll
      for (int ni = 0; ni < 4; ++ni)
        bfr[ni] = *(const bf16x8*)(bufB + ((wc * 64 + ni * 16) << 6) + loff);

      if (t + 3 < NT) stage((to + 3) & 3, t + 3);

      asm volatile("s_waitcnt lgkmcnt(0)" ::: "memory");
      __builtin_amdgcn_sched_barrier(0);
      __builtin_amdgcn_s_setprio(1);
#pragma unroll
      for (int mi = 0; mi < 8; ++mi)
#pragma unroll
        for (int ni = 0; ni < 4; ++ni)
          acc[mi][ni] = __builtin_amdgcn_mfma_f32_16x16x32_bf16(af[mi], bfr[ni], acc[mi][ni], 0, 0, 0);
      __builtin_amdgcn_s_setprio(0);
    }
  }

  __builtin_amdgcn_s_barrier();
  const int rowb = bm * 256 + wr * 128;
  const int colb = bn * 256 + wc * 64;
  unsigned short* myl = (wave < 4) ? &sA[wave][0] : &sB[wave - 4][0];
#pragma unroll
  for (int ni = 0; ni < 4; ++ni) {
    const float bv = bias[colb + ni * 16 + lc];
#pragma unroll
    for (int mf = 0; mf < 8; ++mf)
#pragma unroll
      for (int jj = 0; jj < 4; ++jj)
        myl[(mf * 16 + lr * 4 + jj) * 64 + ni * 16 + lc] = f2bf(acc[mf][ni][jj] + bv);
  }
  asm volatile("" ::: "memory");
#pragma unroll
  for (int i = 0; i < 16; ++i) {
    const int idx2 = i * 64 + lane;
    const int r = idx2 >> 3, c = idx2 & 7;
    *(u16x8*)&Cbf[(size_t)(rowb + r) * N + colb + c * 8] = *(const u16x8*)&myl[r * 64 + c * 8];
  }
}

// ---------------- gemm2 (out-proj): 256x128 tile, 8 waves, 3-deep -----------
// 4M x 2N waves; per wave 64x64 out (16 MFMA, 8 ds_read_b128).  3 gloads per
// thread per tile (A x2 + B x1); counted vmcnt(3) at tile entry (stage t+2;
// t+1's 3 loads stay in flight); vmcnt(0) only at the last tile.  LDS 72 KB
// (3 x 16KB A + 3 x 8KB B) -> 2 blocks/CU, all 320 blocks resident.
__global__ __launch_bounds__(512, 2)
void k_gemm_out(const unsigned short* __restrict__ A,
                const unsigned short* __restrict__ Bt,
                const float* __restrict__ bias,
                float* __restrict__ Cf,
                int M, int N, int K) {
  __shared__ unsigned short sA[3][8192];   // [256][32] per buf
  __shared__ unsigned short sB[3][4096];   // [128][32] per buf
  const int nbm = M >> 8, nbn = N >> 7;     // 16, 20
  const int CM = nbm >> 2, CN = nbn >> 1;   // 4, 10
  int wg = blockIdx.x;
  const int xcd = wg & 7;
  const int idx = wg >> 3;
  const int bm = (xcd >> 1) * CM + idx / CN;
  const int bn = (xcd & 1) * CN + idx % CN;
  const int tid = threadIdx.x;
  const int lane = tid & 63, wave = tid >> 6;
  const int wr = wave >> 1, wc = wave & 1;  // 4 (M) x 2 (N)
  const int lc = lane & 15, lr = lane >> 4;

  const int sub = (lane & 7) ^ (lane >> 3);
  const int rstage = wave * 16 + ((lane >> 3) << 1) + (sub >> 2);
  const int cstage = (sub & 3) * 8;
  const unsigned short* Agp = A + (size_t)(bm * 256 + rstage) * K + cstage;
  const unsigned short* Bgp = Bt + (size_t)(bn * 128 + rstage) * K + cstage;
  const size_t halfoff = (size_t)128 * K;

  const int loff = ((lc >> 1) << 7) + (((((lc & 1) << 2) | lr) ^ (lc >> 1)) << 4);

  f32x4 acc[4][4];
  const f32x4 zero = {0.f, 0.f, 0.f, 0.f};
#pragma unroll
  for (int m = 0; m < 4; ++m)
#pragma unroll
    for (int n = 0; n < 4; ++n) acc[m][n] = zero;

  auto stage = [&](int buf, int t) {
    gload16(Agp + t * 32, &sA[buf][wave * 512]);
    gload16(Agp + halfoff + t * 32, &sA[buf][4096 + wave * 512]);
    gload16(Bgp + t * 32, &sB[buf][wave * 512]);
  };

  const int NT = K >> 5;   // 80
  stage(0, 0);
  stage(1, 1);
  int b0 = 0;
  for (int t = 0; t < NT; ++t) {
    if (t < NT - 1) asm volatile("s_waitcnt vmcnt(3)" ::: "memory");
    else            asm volatile("s_waitcnt vmcnt(0)" ::: "memory");
    __builtin_amdgcn_s_barrier();
    asm volatile("" ::: "memory");

    const char* bufA = (const char*)&sA[b0][0];
    const char* bufB = (const char*)&sB[b0][0];
    bf16x8 af[4], bfr[4];
#pragma unroll
    for (int mi = 0; mi < 4; ++mi)
      af[mi] = *(const bf16x8*)(bufA + ((wr * 64 + mi * 16) << 6) + loff);
#pragma unroll
    for (int ni = 0; ni < 4; ++ni)
      bfr[ni] = *(const bf16x8*)(bufB + ((wc * 64 + ni * 16) << 6) + loff);

    if (t + 2 < NT) {
      int bs = b0 - 1; if (bs < 0) bs = 2;   // (t+2)%3
      stage(bs, t + 2);
    }

    asm volatile("s_waitcnt lgkmcnt(0)" ::: "memory");
    __builtin_amdgcn_sched_barrier(0);
    __builtin_amdgcn_s_setprio(1);
#pragma unroll
    for (int mi = 0; mi < 4; ++mi)
#pragma unroll
      for (int ni = 0; ni < 4; ++ni)
        acc[mi][ni] = __builtin_amdgcn_mfma_f32_16x16x32_bf16(af[mi], bfr[ni], acc[mi][ni], 0, 0, 0);
    __builtin_amdgcn_s_setprio(0);
    ++b0; if (b0 == 3) b0 = 0;
  }

  // epilogue: 2-pass per-wave LDS relayout -> coalesced float4 stores
  __builtin_amdgcn_s_barrier();
  const int rowb = bm * 256 + wr * 64;
  const int colb = bn * 128 + wc * 64;
  float* fw = (float*)&sA[0][0] + wave * 2112;   // 32 rows x 66 f32 per wave (67.6KB)
#pragma unroll
  for (int p2 = 0; p2 < 2; ++p2) {
#pragma unroll
    for (int mfi = 0; mfi < 2; ++mfi) {
      const int mf = p2 * 2 + mfi;
#pragma unroll
      for (int ni = 0; ni < 4; ++ni) {
        const float bv = bias[colb + ni * 16 + lc];
#pragma unroll
        for (int jj = 0; jj < 4; ++jj)
          fw[(mfi * 16 + lr * 4 + jj) * 66 + ni * 16 + lc] = acc[mf][ni][jj] + bv;
      }
    }
    asm volatile("" ::: "memory");
#pragma unroll
    for (int i = 0; i < 8; ++i) {
      const int idx2 = i * 64 + lane;
      const int r = idx2 >> 4, c4 = idx2 & 15;
      *(float4*)&Cf[(size_t)(rowb + p2 * 32 + r) * N + colb + c4 * 4] =
          *(const float4*)&fw[r * 66 + c4 * 4];
    }
    asm volatile("" ::: "memory");
  }
}

// ---------------- RoPE + head split: qkv -> Q (scaled), K, V^T --------------
__global__ __launch_bounds__(256) void k_rope(const unsigned short* __restrict__ qkv,
                                              unsigned short* __restrict__ Qw,
                                              unsigned short* __restrict__ Kw,
                                              unsigned short* __restrict__ Vt) {
  const int blk = blockIdx.x;
  const int sc = blk & 31;
  const int bh = blk >> 5;
  const int b = bh >> 5, h = bh & 31;
  const int s0 = sc * 64;
  __shared__ float cs0[64][16], sn0[64][16];
  __shared__ unsigned short vbuf[64][88];
  const int tid = threadIdx.x;
  for (int i = tid; i < 64 * 16; i += 256) {
    int sl = i >> 4, fi = i & 15;
    float ang = (float)(s0 + sl) * __expf(-(float)fi * 0.575646273248511421f);
    cs0[sl][fi] = cosf(ang);
    sn0[sl][fi] = sinf(ang);
  }
  const size_t row0 = (size_t)(b * S_LEN + s0) * QKV_N;
  for (int i = tid; i < 64 * 10; i += 256) {
    int sl = i / 10, o = i - sl * 10;
    *(u16x8*)&vbuf[sl][o * 8] =
        *(const u16x8*)&qkv[row0 + (size_t)sl * QKV_N + 2 * HIDDEN + h * HD + o * 8];
  }
  __syncthreads();
  const size_t obase = ((size_t)bh * S_LEN + s0) * DPAD;
  const float SCALE = 0.111803398874989485f;  // 80^-0.5
  for (int i = tid; i < 64 * 12; i += 256) {
    int sl = i / 12, o = i - sl * 12;
    u16x8 outq = {0, 0, 0, 0, 0, 0, 0, 0};
    u16x8 outk = {0, 0, 0, 0, 0, 0, 0, 0};
    if (o < 10) {
      const unsigned short* rp = qkv + row0 + (size_t)sl * QKV_N + h * HD;
      u16x8 xq = *(const u16x8*)(rp + o * 8);
      u16x8 xk = *(const u16x8*)(rp + HIDDEN + o * 8);
      if (o < 2) {
        u16x8 yq = *(const u16x8*)(rp + (o + 2) * 8);
        u16x8 yk = *(const u16x8*)(rp + HIDDEN + (o + 2) * 8);
#pragma unroll
        for (int j = 0; j < 8; ++j) {
          float c = cs0[sl][o * 8 + j], s = sn0[sl][o * 8 + j];
          outq[j] = f2bf((bf2f(xq[j]) * c - bf2f(yq[j]) * s) * SCALE);
          outk[j] = f2bf(bf2f(xk[j]) * c - bf2f(yk[j]) * s);
        }
      } else if (o < 4) {
        u16x8 yq = *(const u16x8*)(rp + (o - 2) * 8);
        u16x8 yk = *(const u16x8*)(rp + HIDDEN + (o - 2) * 8);
#pragma unroll
        for (int j = 0; j < 8; ++j) {
          float c = cs0[sl][(o - 2) * 8 + j], s = sn0[sl][(o - 2) * 8 + j];
          outq[j] = f2bf((bf2f(xq[j]) * c + bf2f(yq[j]) * s) * SCALE);
          outk[j] = f2bf(bf2f(xk[j]) * c + bf2f(yk[j]) * s);
        }
      } else {
#pragma unroll
        for (int j = 0; j < 8; ++j) {
          outq[j] = f2bf(bf2f(xq[j]) * SCALE);
          outk[j] = xk[j];
        }
      }
    }
    *(u16x8*)&Qw[obase + (size_t)sl * DPAD + o * 8] = outq;
    *(u16x8*)&Kw[obase + (size_t)sl * DPAD + o * 8] = outk;
  }
  const size_t vtb = (size_t)bh * DPAD * S_LEN + s0;
  for (int i = tid; i < 80 * 8; i += 256) {
    int d = i >> 3, so = i & 7;
    u16x8 v;
#pragma unroll
    for (int j = 0; j < 8; ++j) v[j] = vbuf[so * 8 + j][d];
    *(u16x8*)&Vt[vtb + (size_t)d * S_LEN + so * 8] = v;
  }
}

// ---------------- flash attention (causal), R15-exact ------------------------
__global__ __launch_bounds__(256, 2) void k_attn(const unsigned short* __restrict__ Qw,
                                                 const unsigned short* __restrict__ Kw,
                                                 const unsigned short* __restrict__ Vt,
                                                 unsigned short* __restrict__ O) {
  __shared__ unsigned short sK[2][64 * 104];
  __shared__ unsigned short sV[2][80 * 72];
  __shared__ unsigned short sP[4][16 * 72];
  const int p = blockIdx.x >> 6;
  const int bh = blockIdx.x & 63;
  const int b = bh >> 5, h = bh & 31;
  const int tid = threadIdx.x;
  const int wave = tid >> 6, lane = tid & 63;
  const int lr = lane >> 4, lc = lane & 15;
  unsigned short* Pw = &sP[wave][0];

  const unsigned short* Kh = Kw + (size_t)bh * S_LEN * DPAD;
  const unsigned short* Vh = Vt + (size_t)bh * DPAD * S_LEN;
  const unsigned short* Qh = Qw + (size_t)bh * S_LEN * DPAD;

  const int kr = tid >> 2, kc = (tid & 3) * 24;
  const int vr = tid >> 3, vc = (tid & 7) * 8;

  u16x8 kst0, kst1, kst2, vst0, vst1, vst2;
  auto gload = [&](int t) {
    const unsigned short* Kg = Kh + ((size_t)(t * 64 + kr)) * DPAD + kc;
    kst0 = *(const u16x8*)(Kg);
    kst1 = *(const u16x8*)(Kg + 8);
    kst2 = *(const u16x8*)(Kg + 16);
    const unsigned short* Vg = Vh + (size_t)vr * S_LEN + t * 64 + vc;
    vst0 = *(const u16x8*)(Vg);
    vst1 = *(const u16x8*)(Vg + 32 * S_LEN);
    if (tid < 128) vst2 = *(const u16x8*)(Vg + (size_t)64 * S_LEN);
  };
  auto swrite = [&](int buf) {
    *(u16x8*)&sK[buf][kr * 104 + kc] = kst0;
    *(u16x8*)&sK[buf][kr * 104 + kc + 8] = kst1;
    *(u16x8*)&sK[buf][kr * 104 + kc + 16] = kst2;
    *(u16x8*)&sV[buf][vr * 72 + vc] = vst0;
    *(u16x8*)&sV[buf][(vr + 32) * 72 + vc] = vst1;
    if (tid < 128) *(u16x8*)&sV[buf][(vr + 64) * 72 + vc] = vst2;
  };

  const f32x4 zero = {0.f, 0.f, 0.f, 0.f};

#pragma unroll 1
  for (int qi = 0; qi < 2; ++qi) {
    const int qt = qi ? (15 - p) : p;
    const int nt = 2 * qt + 2;
    const int wbase = qt * 128 + wave * 32;

    bf16x8 qf[2][3];
#pragma unroll
    for (int m = 0; m < 2; ++m)
#pragma unroll
      for (int ks = 0; ks < 3; ++ks)
        qf[m][ks] = *(const bf16x8*)&Qh[(size_t)(wbase + m * 16 + lc) * DPAD + ks * 32 + lr * 8];

    f32x4 oacc[2][5];
#pragma unroll
    for (int m = 0; m < 2; ++m)
#pragma unroll
      for (int n = 0; n < 5; ++n) oacc[m][n] = zero;
    float mrun[2] = {-1e30f, -1e30f}, lrun[2] = {0.f, 0.f};

    gload(0);
    __syncthreads();
    swrite(0);
    int cur = 0;

#pragma unroll 1
    for (int t = 0; t < nt; ++t) {
      __syncthreads();
      if (t + 1 < nt) gload(t + 1);
      const int ktb = t * 64;
      const bool act0 = ktb <= wbase + 15;
      const bool act1 = ktb <= wbase + 31;
      if (act1) {
        const unsigned short* Kc = sK[cur];
        const unsigned short* Vc = sV[cur];
        f32x4 sf[2][4];
#pragma unroll
        for (int n = 0; n < 4; ++n) {
          sf[0][n] = zero; sf[1][n] = zero;
#pragma unroll
          for (int ks = 0; ks < 3; ++ks) {
            bf16x8 kf = *(const bf16x8*)&Kc[(n * 16 + lc) * 104 + ks * 32 + lr * 8];
            if (act0) sf[0][n] = __builtin_amdgcn_mfma_f32_16x16x32_bf16(kf, qf[0][ks], sf[0][n], 0, 0, 0);
            sf[1][n] = __builtin_amdgcn_mfma_f32_16x16x32_bf16(kf, qf[1][ks], sf[1][n], 0, 0, 0);
          }
        }
        bf16x8 vf[5][2];
#pragma unroll
        for (int n = 0; n < 5; ++n)
#pragma unroll
          for (int ks = 0; ks < 2; ++ks)
            vf[n][ks] = *(const bf16x8*)&Vc[(n * 16 + lc) * 72 + ks * 32 + lr * 8];
#pragma unroll
        for (int m = 0; m < 2; ++m) {
          if (m == 0 && !act0) continue;
          const int qrow0 = wbase + m * 16;
          if (ktb + 63 > qrow0) {
#pragma unroll
            for (int n = 0; n < 4; ++n)
#pragma unroll
              for (int j = 0; j < 4; ++j)
                if (ktb + n * 16 + lr * 4 + j > qrow0 + lc) sf[m][n][j] = -1e30f;
          }
          float t0 = sf[m][0][0];
#pragma unroll
          for (int n = 0; n < 4; ++n)
#pragma unroll
            for (int j = 0; j < 4; ++j) t0 = fmaxf(t0, sf[m][n][j]);
          t0 = fmaxf(t0, __shfl_xor(t0, 16));
          t0 = fmaxf(t0, __shfl_xor(t0, 32));
          const bool need = __any(t0 > mrun[m] + 8.f);
          const float nm = need ? fmaxf(mrun[m], t0) : mrun[m];
          float ps = 0.f;
#pragma unroll
          for (int n = 0; n < 4; ++n)
#pragma unroll
            for (int j = 0; j < 4; ++j) {
              float e = __expf(sf[m][n][j] - nm);
              sf[m][n][j] = e;
              ps += e;
            }
          ps += __shfl_xor(ps, 16);
          ps += __shfl_xor(ps, 32);
          if (need) {
            const float corrq = __expf(mrun[m] - nm);
            mrun[m] = nm;
            lrun[m] = lrun[m] * corrq + ps;
            float cj[4];
#pragma unroll
            for (int j = 0; j < 4; ++j) cj[j] = __shfl(corrq, lr * 4 + j, 16);
#pragma unroll
            for (int n = 0; n < 5; ++n)
#pragma unroll
              for (int j = 0; j < 4; ++j) oacc[m][n][j] *= cj[j];
          } else {
            lrun[m] += ps;
          }
#pragma unroll
          for (int n = 0; n < 4; ++n) {
            unsigned lo = (unsigned)f2bf(sf[m][n][0]) | ((unsigned)f2bf(sf[m][n][1]) << 16);
            unsigned hi = (unsigned)f2bf(sf[m][n][2]) | ((unsigned)f2bf(sf[m][n][3]) << 16);
            uint2 u; u.x = lo; u.y = hi;
            *(uint2*)&Pw[lc * 72 + n * 16 + lr * 4] = u;
          }
          asm volatile("" ::: "memory");
          bf16x8 pa0 = *(const bf16x8*)&Pw[lc * 72 + lr * 8];
          bf16x8 pa1 = *(const bf16x8*)&Pw[lc * 72 + 32 + lr * 8];
#pragma unroll
          for (int n = 0; n < 5; ++n) {
            oacc[m][n] = __builtin_amdgcn_mfma_f32_16x16x32_bf16(pa0, vf[n][0], oacc[m][n], 0, 0, 0);
            oacc[m][n] = __builtin_amdgcn_mfma_f32_16x16x32_bf16(pa1, vf[n][1], oacc[m][n], 0, 0, 0);
          }
          asm volatile("" ::: "memory");
        }
      }
      if (t + 1 < nt) swrite(cur ^ 1);
      cur ^= 1;
    }

#pragma unroll
    for (int m = 0; m < 2; ++m) {
      float linv[4];
#pragma unroll
      for (int j = 0; j < 4; ++j) {
        float lj = __shfl(lrun[m], lr * 4 + j, 16);
        linv[j] = 1.f / lj;
      }
      const int q0 = wbase + m * 16 + lr * 4;
#pragma unroll
      for (int n = 0; n < 5; ++n) {
        const int d = n * 16 + lc;
#pragma unroll
        for (int j = 0; j < 4; ++j)
          O[((size_t)(b * S_LEN) + q0 + j) * HIDDEN + h * HD + d] = f2bf(oacc[m][n][j] * linv[j]);
      }
    }
  }
}

extern "C" void kernel_launch(void* const* d_in, const int* in_sizes, int n_in,
                              void* d_out, int out_size, void* d_ws, size_t ws_size,
                              hipStream_t stream) {
  (void)in_sizes; (void)n_in; (void)out_size; (void)ws_size;
  const float* hidden  = (const float*)d_in[1];
  const float* w_qkv   = (const float*)d_in[2];
  const float* b_qkv   = (const float*)d_in[3];
  const float* w_dense = (const float*)d_in[4];
  const float* b_dense = (const float*)d_in[5];
  char* ws = (char*)d_ws;
  unsigned short* Abf   = (unsigned short*)(ws + 0);          // 4096x2560 bf16
  unsigned short* Wqkvt = (unsigned short*)(ws + 20971520);   // 7680x2560 bf16
  unsigned short* Wdt   = (unsigned short*)(ws + 60293120);   // 2560x2560 bf16
  unsigned short* QKVb  = (unsigned short*)(ws + 73400320);   // 4096x7680 bf16
  unsigned short* Qw    = (unsigned short*)(ws + 136314880);  // 64x2048x96 bf16
  unsigned short* Kw    = (unsigned short*)(ws + 161480704);
  unsigned short* Vt    = (unsigned short*)(ws + 186646528);
  unsigned short* Obf   = (unsigned short*)(ws + 211812352);  // 4096x2560 bf16

  k_prep<<<16640, 256, 0, stream>>>(hidden, Abf, w_qkv, Wqkvt, w_dense, Wdt);
  k_gemm_qkv<<<480, 512, 0, stream>>>(Abf, Wqkvt, b_qkv, QKVb, 4096, 7680, 2560);
  k_rope<<<2048, 256, 0, stream>>>(QKVb, Qw, Kw, Vt);
  k_attn<<<512, 256, 0, stream>>>(Qw, Kw, Vt, Obf);
  k_gemm_out<<<320, 512, 0, stream>>>(Obf, Wdt, b_dense, (float*)d_out, 4096, 2560, 2560);
}